// Round 1
// baseline (1529.797 us; speedup 1.0000x reference)
//
#include <hip/hip_runtime.h>
#include <hip/hip_bf16.h>
#include <math.h>

#define L_    512
#define F_    64
#define M_    (F_*L_)   // 32768
#define D2_   128
#define H_    256
#define DIN0_ 259

// ---------------- geometry: center + covariance + 3x3 eigh ----------------
__global__ void geom_kernel(const float* __restrict__ cords, const float* __restrict__ mask,
                            float* __restrict__ misc) {
  int b = blockIdx.x;
  int t = threadIdx.x;
  __shared__ float red[4][256];
  float sx=0.f, sy=0.f, sz=0.f, sm=0.f;
  for (int l = t; l < 512; l += 256) {
    float m = mask[b*512 + l];
    const float* X = cords + ((size_t)(b*512 + l)*4 + 1)*3;
    sx += X[0]*m; sy += X[1]*m; sz += X[2]*m; sm += m;
  }
  red[0][t]=sx; red[1][t]=sy; red[2][t]=sz; red[3][t]=sm;
  __syncthreads();
  for (int off=128; off>0; off>>=1) {
    if (t < off) { red[0][t]+=red[0][t+off]; red[1][t]+=red[1][t+off];
                   red[2][t]+=red[2][t+off]; red[3][t]+=red[3][t+off]; }
    __syncthreads();
  }
  float inv = 1.f/red[3][0];
  float cx = red[0][0]*inv, cy = red[1][0]*inv, cz = red[2][0]*inv;
  __syncthreads();
  __shared__ float red6[6][256];
  float c00=0,c01=0,c02=0,c11=0,c12=0,c22=0;
  for (int l = t; l < 512; l += 256) {
    float m = mask[b*512+l];
    const float* X = cords + ((size_t)(b*512+l)*4 + 1)*3;
    float x = X[0]-cx*m, y = X[1]-cy*m, z = X[2]-cz*m;
    c00+=x*x; c01+=x*y; c02+=x*z; c11+=y*y; c12+=y*z; c22+=z*z;
  }
  red6[0][t]=c00; red6[1][t]=c01; red6[2][t]=c02;
  red6[3][t]=c11; red6[4][t]=c12; red6[5][t]=c22;
  __syncthreads();
  for (int off=128; off>0; off>>=1) {
    if (t < off) for (int j=0;j<6;j++) red6[j][t]+=red6[j][t+off];
    __syncthreads();
  }
  if (t == 0) {
    double A[3][3], V[3][3];
    A[0][0]=red6[0][0]; A[0][1]=A[1][0]=red6[1][0]; A[0][2]=A[2][0]=red6[2][0];
    A[1][1]=red6[3][0]; A[1][2]=A[2][1]=red6[4][0]; A[2][2]=red6[5][0];
    for (int j=0;j<3;j++) for (int i=0;i<3;i++) V[j][i] = (i==j)?1.0:0.0;
    for (int sweep=0; sweep<10; ++sweep) {
      for (int p=0;p<2;p++) for (int q=p+1;q<3;q++) {
        double apq = A[p][q];
        if (fabs(apq) < 1e-18) continue;
        double app = A[p][p], aqq = A[q][q];
        double tau = (aqq - app) / (2.0*apq);
        double tt = (tau >= 0.0) ? 1.0/(tau + sqrt(1.0+tau*tau))
                                 : 1.0/(tau - sqrt(1.0+tau*tau));
        double cc = 1.0/sqrt(1.0+tt*tt), ss = tt*cc;
        A[p][p] = app - tt*apq;
        A[q][q] = aqq + tt*apq;
        A[p][q] = A[q][p] = 0.0;
        int r = 3 - p - q;
        double arp = A[r][p], arq = A[r][q];
        A[r][p] = A[p][r] = cc*arp - ss*arq;
        A[r][q] = A[q][r] = ss*arp + cc*arq;
        for (int rr2=0; rr2<3; ++rr2) {
          double vrp = V[rr2][p], vrq = V[rr2][q];
          V[rr2][p] = cc*vrp - ss*vrq;
          V[rr2][q] = ss*vrp + cc*vrq;
        }
      }
    }
    double w[3] = {A[0][0], A[1][1], A[2][2]};
    int idx[3] = {0,1,2};
    for (int i=0;i<2;i++) for (int j=0;j<2-i;j++)
      if (w[idx[j]] > w[idx[j+1]]) { int tmp=idx[j]; idx[j]=idx[j+1]; idx[j+1]=tmp; }
    for (int jj=0;jj<3;jj++) for (int ii=0;ii<3;ii++)
      misc[b*12 + jj*3 + ii] = (float)V[jj][idx[ii]];
    misc[b*12+9]=cx; misc[b*12+10]=cy; misc[b*12+11]=cz;
  }
}

// ---------------- build h0: [F, L, 259] = [hX(3) | emb(256)] ----------------
__global__ void build_h0(const int* __restrict__ seqs, const float* __restrict__ cords,
                         const float* __restrict__ mask, const float* __restrict__ emb,
                         const float* __restrict__ misc, float* __restrict__ h0) {
  int t = threadIdx.x;
  int r = blockIdx.x*4 + (t >> 6);
  int lane = t & 63;
  int f = r >> 9, l = r & 511;
  int b = f >> 3, o = f & 7;
  float* row = h0 + (size_t)r * DIN0_;
  if (lane == 0) {
    float m = mask[b*512 + l];
    const float* X = cords + ((size_t)(b*512 + l)*4 + 1)*3;
    const float* mb = misc + b*12;
    float x = X[0]-mb[9]*m, y = X[1]-mb[10]*m, z = X[2]-mb[11]*m;
    #pragma unroll
    for (int i=0;i<3;i++) {
      float sgn = ((o >> (2-i)) & 1) ? 1.f : -1.f;
      row[i] = sgn * (mb[0+i]*x + mb[3+i]*y + mb[6+i]*z);
    }
  }
  int s = seqs[b*512 + l];
  if (s < 0) s = 82;
  const float4 e4 = *((const float4*)(emb + (size_t)s*256) + lane);
  row[3 + lane*4 + 0] = e4.x;
  row[3 + lane*4 + 1] = e4.y;
  row[3 + lane*4 + 2] = e4.z;
  row[3 + lane*4 + 3] = e4.w;
}

// ---------------- generic fp32 NN GEMM (M,N multiples of 64) ----------------
__global__ __launch_bounds__(256) void gemm_nn(const float* __restrict__ A, const float* __restrict__ B,
                                               float* __restrict__ C,
                                               int M, int N, int K, int lda, int ldb, int ldc) {
  __shared__ float As[32][68];
  __shared__ float Bs[32][64];
  const int bm = blockIdx.x * 64, bn = blockIdx.y * 64;
  const int t = threadIdx.x;
  const int tx = t & 15, ty = t >> 4;
  float acc[4][4] = {};
  for (int k0 = 0; k0 < K; k0 += 32) {
    #pragma unroll
    for (int i = 0; i < 8; i++) {
      int idx = t + i*256;
      int kk = idx & 31, m = idx >> 5;
      int gk = k0 + kk;
      As[kk][m] = (gk < K) ? A[(size_t)(bm + m)*lda + gk] : 0.f;
    }
    #pragma unroll
    for (int i = 0; i < 8; i++) {
      int idx = t + i*256;
      int n = idx & 63, kk = idx >> 6;
      int gk = k0 + kk;
      Bs[kk][n] = (gk < K) ? B[(size_t)gk*ldb + bn + n] : 0.f;
    }
    __syncthreads();
    #pragma unroll
    for (int kk = 0; kk < 32; kk++) {
      float4 a4 = *(const float4*)&As[kk][ty*4];
      float4 b4 = *(const float4*)&Bs[kk][tx*4];
      float av[4] = {a4.x,a4.y,a4.z,a4.w};
      float bv[4] = {b4.x,b4.y,b4.z,b4.w};
      #pragma unroll
      for (int i=0;i<4;i++)
        #pragma unroll
        for (int j=0;j<4;j++)
          acc[i][j] += av[i]*bv[j];
    }
    __syncthreads();
  }
  #pragma unroll
  for (int i=0;i<4;i++) {
    size_t crow = (size_t)(bm + ty*4 + i)*ldc + bn;
    #pragma unroll
    for (int j=0;j<4;j++)
      C[crow + tx*4 + j] = acc[i][j];
  }
}

// ---------------- batched S = q @ k^T * scale, masked ----------------
__global__ __launch_bounds__(256) void gemm_qkT(const float* __restrict__ q, const float* __restrict__ k,
                                                float* __restrict__ S, const float* __restrict__ mask,
                                                float scale) {
  const int f = blockIdx.z;
  const float* A  = q + (size_t)f*512*128;
  const float* Bm = k + (size_t)f*512*128;
  float* Cm = S + (size_t)f*512*512;
  const int bm = blockIdx.x*64, bn = blockIdx.y*64;
  const int t = threadIdx.x, tx = t & 15, ty = t >> 4;
  __shared__ float As[32][68];
  __shared__ float Bs[32][68];
  float acc[4][4] = {};
  for (int k0 = 0; k0 < 128; k0 += 32) {
    #pragma unroll
    for (int i = 0; i < 8; i++) {
      int idx = t + i*256;
      int kk = idx & 31, m = idx >> 5;
      As[kk][m] = A [(size_t)(bm+m)*128 + k0 + kk];
      Bs[kk][m] = Bm[(size_t)(bn+m)*128 + k0 + kk];
    }
    __syncthreads();
    #pragma unroll
    for (int kk = 0; kk < 32; kk++) {
      float4 a4 = *(const float4*)&As[kk][ty*4];
      float4 b4 = *(const float4*)&Bs[kk][tx*4];
      float av[4] = {a4.x,a4.y,a4.z,a4.w};
      float bv[4] = {b4.x,b4.y,b4.z,b4.w};
      #pragma unroll
      for (int i=0;i<4;i++)
        #pragma unroll
        for (int j=0;j<4;j++)
          acc[i][j] += av[i]*bv[j];
    }
    __syncthreads();
  }
  const float* mrow = mask + (f>>3)*512 + bn;
  #pragma unroll
  for (int i=0;i<4;i++) {
    size_t crow = (size_t)(bm + ty*4 + i)*512 + bn;
    #pragma unroll
    for (int j=0;j<4;j++) {
      float val = acc[i][j]*scale;
      if (mrow[tx*4+j] == 0.f) val = -1e9f;
      Cm[crow + tx*4 + j] = val;
    }
  }
}

// ---------------- row softmax over 512 ----------------
__global__ void softmax_rows(float* __restrict__ S) {
  size_t row = blockIdx.x;
  float* p = S + row*512;
  int t = threadIdx.x; // 64
  float v[8];
  float mx = -1e30f;
  #pragma unroll
  for (int i=0;i<8;i++) { v[i] = p[t + i*64]; mx = fmaxf(mx, v[i]); }
  #pragma unroll
  for (int off=32; off>0; off>>=1) mx = fmaxf(mx, __shfl_xor(mx, off));
  float sum = 0.f;
  #pragma unroll
  for (int i=0;i<8;i++) { v[i] = __expf(v[i]-mx); sum += v[i]; }
  #pragma unroll
  for (int off=32; off>0; off>>=1) sum += __shfl_xor(sum, off);
  float invs = 1.f/sum;
  #pragma unroll
  for (int i=0;i<8;i++) p[t + i*64] = v[i]*invs;
}

// ---------------- batched a = P @ v + q ----------------
__global__ __launch_bounds__(256) void gemm_pv(const float* __restrict__ S, const float* __restrict__ v,
                                               const float* __restrict__ q, float* __restrict__ a) {
  const int f = blockIdx.z;
  const float* A  = S + (size_t)f*512*512;
  const float* Bm = v + (size_t)f*512*128;
  const float* Rm = q + (size_t)f*512*128;
  float* Cm = a + (size_t)f*512*128;
  const int bm = blockIdx.x*64, bn = blockIdx.y*64;
  const int t = threadIdx.x, tx = t & 15, ty = t >> 4;
  __shared__ float As[32][68];
  __shared__ float Bs[32][64];
  float acc[4][4] = {};
  for (int k0 = 0; k0 < 512; k0 += 32) {
    #pragma unroll
    for (int i = 0; i < 8; i++) {
      int idx = t + i*256;
      int kk = idx & 31, m = idx >> 5;
      As[kk][m] = A[(size_t)(bm+m)*512 + k0 + kk];
    }
    #pragma unroll
    for (int i = 0; i < 8; i++) {
      int idx = t + i*256;
      int n = idx & 63, kk = idx >> 6;
      Bs[kk][n] = Bm[(size_t)(k0+kk)*128 + bn + n];
    }
    __syncthreads();
    #pragma unroll
    for (int kk = 0; kk < 32; kk++) {
      float4 a4 = *(const float4*)&As[kk][ty*4];
      float4 b4 = *(const float4*)&Bs[kk][tx*4];
      float av[4] = {a4.x,a4.y,a4.z,a4.w};
      float bv[4] = {b4.x,b4.y,b4.z,b4.w};
      #pragma unroll
      for (int i=0;i<4;i++)
        #pragma unroll
        for (int j=0;j<4;j++)
          acc[i][j] += av[i]*bv[j];
    }
    __syncthreads();
  }
  #pragma unroll
  for (int i=0;i<4;i++) {
    size_t crow = (size_t)(bm + ty*4 + i)*128 + bn;
    #pragma unroll
    for (int j=0;j<4;j++)
      Cm[crow + tx*4 + j] = acc[i][j] + Rm[crow + tx*4 + j];
  }
}

// ---------------- sequential SRU scan (one dir), depth-8 prefetch ----------------
__global__ __launch_bounds__(128) void sru_scan(const float* __restrict__ U, const float* __restrict__ mask,
                          const float* __restrict__ vf, const float* __restrict__ vr,
                          const float* __restrict__ bf, const float* __restrict__ br,
                          float* __restrict__ hout, int dir) {
  const int f = blockIdx.x;   // 64
  const int d = threadIdx.x;  // 128
  const int b = f >> 3;
  __shared__ float msk[512];
  for (int i = d; i < 512; i += 128) msk[i] = mask[b*512 + i];
  __syncthreads();
  const float vfd = vf[d], vrd = vr[d], bfd = bf[d], brd = br[d];
  const size_t fbase = (size_t)f * 512;
  float u[8][4];
  #pragma unroll
  for (int i = 0; i < 8; i++) {
    int l = dir ? 511 - i : i;
    const float* p = U + (fbase + l)*512 + d;
    u[i][0]=p[0]; u[i][1]=p[128]; u[i][2]=p[256]; u[i][3]=p[384];
  }
  float c = 0.f;
  for (int l0 = 0; l0 < 512; l0 += 8) {
    #pragma unroll
    for (int s = 0; s < 8; s++) {
      const int step = l0 + s;
      const int l = dir ? 511 - step : step;
      const float u0=u[s][0], u1=u[s][1], u2=u[s][2], u3=u[s][3];
      if (step + 8 < 512) {
        const int lp = dir ? 511 - (step+8) : (step+8);
        const float* p = U + (fbase + lp)*512 + d;
        u[s][0]=p[0]; u[s][1]=p[128]; u[s][2]=p[256]; u[s][3]=p[384];
      }
      const float fg = 1.f/(1.f + __expf(-(u1 + vfd*c + bfd)));
      const float rg = 1.f/(1.f + __expf(-(u2 + vrd*c + brd)));
      float cn = fg*c + (1.f-fg)*u0;
      const float m = msk[l];
      if (m == 0.f) cn = c;
      const float h = (m == 0.f) ? 0.f : (rg*cn + (1.f-rg)*u3);
      c = cn;
      hout[(fbase + l)*256 + (size_t)dir*128 + d] = h;
    }
  }
}

// ---------------- mean over 8 sign-frames ----------------
__global__ void mean_kernel(const float* __restrict__ h2, float* __restrict__ out) {
  int i = blockIdx.x*256 + threadIdx.x;   // 0..262143 (float4 units)
  int row = i >> 6;        // b*512 + l
  int c4  = i & 63;
  int b = row >> 9, l = row & 511;
  float ax=0.f, ay=0.f, az=0.f, aw=0.f;
  #pragma unroll
  for (int o=0;o<8;o++) {
    const float4* p = (const float4*)(h2 + ((size_t)((b*8+o)*512 + l))*256) + c4;
    float4 e = *p;
    ax += e.x; ay += e.y; az += e.z; aw += e.w;
  }
  float4 r; r.x = ax*0.125f; r.y = ay*0.125f; r.z = az*0.125f; r.w = aw*0.125f;
  ((float4*)out)[i] = r;
}

extern "C" void kernel_launch(void* const* d_in, const int* in_sizes, int n_in,
                              void* d_out, int out_size, void* d_ws, size_t ws_size,
                              hipStream_t stream) {
  const int*   seqs  = (const int*)d_in[0];
  const float* cords = (const float*)d_in[1];
  const float* mask  = (const float*)d_in[2];
  const float* emb   = (const float*)d_in[3];
  const float* Wq[2] = {(const float*)d_in[4],  (const float*)d_in[12]};
  const float* Wk[2] = {(const float*)d_in[5],  (const float*)d_in[13]};
  const float* Wv[2] = {(const float*)d_in[6],  (const float*)d_in[14]};
  const float* Wu[2] = {(const float*)d_in[7],  (const float*)d_in[15]};
  const float* vf[2] = {(const float*)d_in[8],  (const float*)d_in[16]};
  const float* vr[2] = {(const float*)d_in[9],  (const float*)d_in[17]};
  const float* bfp[2]= {(const float*)d_in[10], (const float*)d_in[18]};
  const float* brp[2]= {(const float*)d_in[11], (const float*)d_in[19]};

  float* ws   = (float*)d_ws;
  float* misc = ws;
  float* h0 = ws + 256;
  float* q  = h0 + (size_t)M_*DIN0_;
  float* k  = q  + (size_t)M_*128;
  float* v  = k  + (size_t)M_*128;
  float* SU = v  + (size_t)M_*128;     // 16,777,216 floats: S then U (per dir)
  float* h1 = SU + (size_t)M_*512;
  float* a  = k;   // k dead after qk^T
  float* h2 = h0;  // h0 dead after layer-0 q

  geom_kernel<<<8, 256, 0, stream>>>(cords, mask, misc);
  build_h0<<<M_/4, 256, 0, stream>>>(seqs, cords, mask, emb, misc, h0);

  const float scale = 0.08838834764831845f; // 1/sqrt(128)
  for (int layer = 0; layer < 2; ++layer) {
    const float* hin = layer ? h1 : h0;
    int Kdim = layer ? 256 : 259;
    float* hout = layer ? h2 : h1;
    gemm_nn<<<dim3(M_/64, 2), 256, 0, stream>>>(hin, Wq[layer], q, M_, 128, Kdim, Kdim, 128, 128);
    gemm_nn<<<dim3(M_/64, 2), 256, 0, stream>>>(q, Wk[layer], k, M_, 128, 128, 128, 128, 128);
    gemm_nn<<<dim3(M_/64, 2), 256, 0, stream>>>(q, Wv[layer], v, M_, 128, 128, 128, 128, 128);
    gemm_qkT<<<dim3(8,8,64), 256, 0, stream>>>(q, k, SU, mask, scale);
    softmax_rows<<<M_, 64, 0, stream>>>(SU);
    gemm_pv<<<dim3(8,2,64), 256, 0, stream>>>(SU, v, q, a);
    for (int dir = 0; dir < 2; ++dir) {
      gemm_nn<<<dim3(M_/64, 8), 256, 0, stream>>>(a, Wu[layer] + dir*512, SU,
                                                  M_, 512, 128, 128, 1024, 512);
      sru_scan<<<64, 128, 0, stream>>>(SU, mask, vf[layer]+dir*128, vr[layer]+dir*128,
                                       bfp[layer]+dir*128, brp[layer]+dir*128, hout, dir);
    }
  }
  mean_kernel<<<1024, 256, 0, stream>>>(h2, (float*)d_out);
}

// Round 2
// 1275.885 us; speedup vs baseline: 1.1990x; 1.1990x over previous
//
#include <hip/hip_runtime.h>
#include <hip/hip_bf16.h>
#include <math.h>

#define L_    512
#define F_    64
#define M_    (F_*L_)   // 32768
#define D2_   128
#define H_    256
#define DIN0_ 259

// ---------------- geometry: center + covariance + 3x3 eigh ----------------
__global__ void geom_kernel(const float* __restrict__ cords, const float* __restrict__ mask,
                            float* __restrict__ misc) {
  int b = blockIdx.x;
  int t = threadIdx.x;
  __shared__ float red[4][256];
  float sx=0.f, sy=0.f, sz=0.f, sm=0.f;
  for (int l = t; l < 512; l += 256) {
    float m = mask[b*512 + l];
    const float* X = cords + ((size_t)(b*512 + l)*4 + 1)*3;
    sx += X[0]*m; sy += X[1]*m; sz += X[2]*m; sm += m;
  }
  red[0][t]=sx; red[1][t]=sy; red[2][t]=sz; red[3][t]=sm;
  __syncthreads();
  for (int off=128; off>0; off>>=1) {
    if (t < off) { red[0][t]+=red[0][t+off]; red[1][t]+=red[1][t+off];
                   red[2][t]+=red[2][t+off]; red[3][t]+=red[3][t+off]; }
    __syncthreads();
  }
  float inv = 1.f/red[3][0];
  float cx = red[0][0]*inv, cy = red[1][0]*inv, cz = red[2][0]*inv;
  __syncthreads();
  __shared__ float red6[6][256];
  float c00=0,c01=0,c02=0,c11=0,c12=0,c22=0;
  for (int l = t; l < 512; l += 256) {
    float m = mask[b*512+l];
    const float* X = cords + ((size_t)(b*512+l)*4 + 1)*3;
    float x = X[0]-cx*m, y = X[1]-cy*m, z = X[2]-cz*m;
    c00+=x*x; c01+=x*y; c02+=x*z; c11+=y*y; c12+=y*z; c22+=z*z;
  }
  red6[0][t]=c00; red6[1][t]=c01; red6[2][t]=c02;
  red6[3][t]=c11; red6[4][t]=c12; red6[5][t]=c22;
  __syncthreads();
  for (int off=128; off>0; off>>=1) {
    if (t < off) for (int j=0;j<6;j++) red6[j][t]+=red6[j][t+off];
    __syncthreads();
  }
  if (t == 0) {
    double A[3][3], V[3][3];
    A[0][0]=red6[0][0]; A[0][1]=A[1][0]=red6[1][0]; A[0][2]=A[2][0]=red6[2][0];
    A[1][1]=red6[3][0]; A[1][2]=A[2][1]=red6[4][0]; A[2][2]=red6[5][0];
    for (int j=0;j<3;j++) for (int i=0;i<3;i++) V[j][i] = (i==j)?1.0:0.0;
    for (int sweep=0; sweep<10; ++sweep) {
      for (int p=0;p<2;p++) for (int q=p+1;q<3;q++) {
        double apq = A[p][q];
        if (fabs(apq) < 1e-18) continue;
        double app = A[p][p], aqq = A[q][q];
        double tau = (aqq - app) / (2.0*apq);
        double tt = (tau >= 0.0) ? 1.0/(tau + sqrt(1.0+tau*tau))
                                 : 1.0/(tau - sqrt(1.0+tau*tau));
        double cc = 1.0/sqrt(1.0+tt*tt), ss = tt*cc;
        A[p][p] = app - tt*apq;
        A[q][q] = aqq + tt*apq;
        A[p][q] = A[q][p] = 0.0;
        int r = 3 - p - q;
        double arp = A[r][p], arq = A[r][q];
        A[r][p] = A[p][r] = cc*arp - ss*arq;
        A[r][q] = A[q][r] = ss*arp + cc*arq;
        for (int rr2=0; rr2<3; ++rr2) {
          double vrp = V[rr2][p], vrq = V[rr2][q];
          V[rr2][p] = cc*vrp - ss*vrq;
          V[rr2][q] = ss*vrp + cc*vrq;
        }
      }
    }
    double w[3] = {A[0][0], A[1][1], A[2][2]};
    int idx[3] = {0,1,2};
    for (int i=0;i<2;i++) for (int j=0;j<2-i;j++)
      if (w[idx[j]] > w[idx[j+1]]) { int tmp=idx[j]; idx[j]=idx[j+1]; idx[j+1]=tmp; }
    for (int jj=0;jj<3;jj++) for (int ii=0;ii<3;ii++)
      misc[b*12 + jj*3 + ii] = (float)V[jj][idx[ii]];
    misc[b*12+9]=cx; misc[b*12+10]=cy; misc[b*12+11]=cz;
  }
}

// ---------------- build h0: [F, L, 259] = [hX(3) | emb(256)] ----------------
__global__ void build_h0(const int* __restrict__ seqs, const float* __restrict__ cords,
                         const float* __restrict__ mask, const float* __restrict__ emb,
                         const float* __restrict__ misc, float* __restrict__ h0) {
  int t = threadIdx.x;
  int r = blockIdx.x*4 + (t >> 6);
  int lane = t & 63;
  int f = r >> 9, l = r & 511;
  int b = f >> 3, o = f & 7;
  float* row = h0 + (size_t)r * DIN0_;
  if (lane == 0) {
    float m = mask[b*512 + l];
    const float* X = cords + ((size_t)(b*512 + l)*4 + 1)*3;
    const float* mb = misc + b*12;
    float x = X[0]-mb[9]*m, y = X[1]-mb[10]*m, z = X[2]-mb[11]*m;
    #pragma unroll
    for (int i=0;i<3;i++) {
      float sgn = ((o >> (2-i)) & 1) ? 1.f : -1.f;
      row[i] = sgn * (mb[0+i]*x + mb[3+i]*y + mb[6+i]*z);
    }
  }
  int s = seqs[b*512 + l];
  if (s < 0) s = 82;
  const float4 e4 = *((const float4*)(emb + (size_t)s*256) + lane);
  row[3 + lane*4 + 0] = e4.x;
  row[3 + lane*4 + 1] = e4.y;
  row[3 + lane*4 + 2] = e4.z;
  row[3 + lane*4 + 3] = e4.w;
}

// ---------------- generic fp32 NN GEMM (M,N multiples of 64) ----------------
__global__ __launch_bounds__(256) void gemm_nn(const float* __restrict__ A, const float* __restrict__ B,
                                               float* __restrict__ C,
                                               int M, int N, int K, int lda, int ldb, int ldc) {
  __shared__ float As[32][68];
  __shared__ float Bs[32][64];
  const int bm = blockIdx.x * 64, bn = blockIdx.y * 64;
  const int t = threadIdx.x;
  const int tx = t & 15, ty = t >> 4;
  float acc[4][4] = {};
  for (int k0 = 0; k0 < K; k0 += 32) {
    #pragma unroll
    for (int i = 0; i < 8; i++) {
      int idx = t + i*256;
      int kk = idx & 31, m = idx >> 5;
      int gk = k0 + kk;
      As[kk][m] = (gk < K) ? A[(size_t)(bm + m)*lda + gk] : 0.f;
    }
    #pragma unroll
    for (int i = 0; i < 8; i++) {
      int idx = t + i*256;
      int n = idx & 63, kk = idx >> 6;
      int gk = k0 + kk;
      Bs[kk][n] = (gk < K) ? B[(size_t)gk*ldb + bn + n] : 0.f;
    }
    __syncthreads();
    #pragma unroll
    for (int kk = 0; kk < 32; kk++) {
      float4 a4 = *(const float4*)&As[kk][ty*4];
      float4 b4 = *(const float4*)&Bs[kk][tx*4];
      float av[4] = {a4.x,a4.y,a4.z,a4.w};
      float bv[4] = {b4.x,b4.y,b4.z,b4.w};
      #pragma unroll
      for (int i=0;i<4;i++)
        #pragma unroll
        for (int j=0;j<4;j++)
          acc[i][j] += av[i]*bv[j];
    }
    __syncthreads();
  }
  #pragma unroll
  for (int i=0;i<4;i++) {
    size_t crow = (size_t)(bm + ty*4 + i)*ldc + bn;
    #pragma unroll
    for (int j=0;j<4;j++)
      C[crow + tx*4 + j] = acc[i][j];
  }
}

// ---------------- batched S = q @ k^T * scale, masked ----------------
__global__ __launch_bounds__(256) void gemm_qkT(const float* __restrict__ q, const float* __restrict__ k,
                                                float* __restrict__ S, const float* __restrict__ mask,
                                                float scale) {
  const int f = blockIdx.z;
  const float* A  = q + (size_t)f*512*128;
  const float* Bm = k + (size_t)f*512*128;
  float* Cm = S + (size_t)f*512*512;
  const int bm = blockIdx.x*64, bn = blockIdx.y*64;
  const int t = threadIdx.x, tx = t & 15, ty = t >> 4;
  __shared__ float As[32][68];
  __shared__ float Bs[32][68];
  float acc[4][4] = {};
  for (int k0 = 0; k0 < 128; k0 += 32) {
    #pragma unroll
    for (int i = 0; i < 8; i++) {
      int idx = t + i*256;
      int kk = idx & 31, m = idx >> 5;
      As[kk][m] = A [(size_t)(bm+m)*128 + k0 + kk];
      Bs[kk][m] = Bm[(size_t)(bn+m)*128 + k0 + kk];
    }
    __syncthreads();
    #pragma unroll
    for (int kk = 0; kk < 32; kk++) {
      float4 a4 = *(const float4*)&As[kk][ty*4];
      float4 b4 = *(const float4*)&Bs[kk][tx*4];
      float av[4] = {a4.x,a4.y,a4.z,a4.w};
      float bv[4] = {b4.x,b4.y,b4.z,b4.w};
      #pragma unroll
      for (int i=0;i<4;i++)
        #pragma unroll
        for (int j=0;j<4;j++)
          acc[i][j] += av[i]*bv[j];
    }
    __syncthreads();
  }
  const float* mrow = mask + (f>>3)*512 + bn;
  #pragma unroll
  for (int i=0;i<4;i++) {
    size_t crow = (size_t)(bm + ty*4 + i)*512 + bn;
    #pragma unroll
    for (int j=0;j<4;j++) {
      float val = acc[i][j]*scale;
      if (mrow[tx*4+j] == 0.f) val = -1e9f;
      Cm[crow + tx*4 + j] = val;
    }
  }
}

// ---------------- row softmax over 512 ----------------
__global__ void softmax_rows(float* __restrict__ S) {
  size_t row = blockIdx.x;
  float* p = S + row*512;
  int t = threadIdx.x; // 64
  float v[8];
  float mx = -1e30f;
  #pragma unroll
  for (int i=0;i<8;i++) { v[i] = p[t + i*64]; mx = fmaxf(mx, v[i]); }
  #pragma unroll
  for (int off=32; off>0; off>>=1) mx = fmaxf(mx, __shfl_xor(mx, off));
  float sum = 0.f;
  #pragma unroll
  for (int i=0;i<8;i++) { v[i] = __expf(v[i]-mx); sum += v[i]; }
  #pragma unroll
  for (int off=32; off>0; off>>=1) sum += __shfl_xor(sum, off);
  float invs = 1.f/sum;
  #pragma unroll
  for (int i=0;i<8;i++) p[t + i*64] = v[i]*invs;
}

// ---------------- batched a = P @ v + q ----------------
__global__ __launch_bounds__(256) void gemm_pv(const float* __restrict__ S, const float* __restrict__ v,
                                               const float* __restrict__ q, float* __restrict__ a) {
  const int f = blockIdx.z;
  const float* A  = S + (size_t)f*512*512;
  const float* Bm = v + (size_t)f*512*128;
  const float* Rm = q + (size_t)f*512*128;
  float* Cm = a + (size_t)f*512*128;
  const int bm = blockIdx.x*64, bn = blockIdx.y*64;
  const int t = threadIdx.x, tx = t & 15, ty = t >> 4;
  __shared__ float As[32][68];
  __shared__ float Bs[32][64];
  float acc[4][4] = {};
  for (int k0 = 0; k0 < 512; k0 += 32) {
    #pragma unroll
    for (int i = 0; i < 8; i++) {
      int idx = t + i*256;
      int kk = idx & 31, m = idx >> 5;
      As[kk][m] = A[(size_t)(bm+m)*512 + k0 + kk];
    }
    #pragma unroll
    for (int i = 0; i < 8; i++) {
      int idx = t + i*256;
      int n = idx & 63, kk = idx >> 6;
      Bs[kk][n] = Bm[(size_t)(k0+kk)*128 + bn + n];
    }
    __syncthreads();
    #pragma unroll
    for (int kk = 0; kk < 32; kk++) {
      float4 a4 = *(const float4*)&As[kk][ty*4];
      float4 b4 = *(const float4*)&Bs[kk][tx*4];
      float av[4] = {a4.x,a4.y,a4.z,a4.w};
      float bv[4] = {b4.x,b4.y,b4.z,b4.w};
      #pragma unroll
      for (int i=0;i<4;i++)
        #pragma unroll
        for (int j=0;j<4;j++)
          acc[i][j] += av[i]*bv[j];
    }
    __syncthreads();
  }
  #pragma unroll
  for (int i=0;i<4;i++) {
    size_t crow = (size_t)(bm + ty*4 + i)*128 + bn;
    #pragma unroll
    for (int j=0;j<4;j++)
      Cm[crow + tx*4 + j] = acc[i][j] + Rm[crow + tx*4 + j];
  }
}

// ---------------- sequential SRU scan, LDS double-buffered streaming ----------------
// grid: 128 blocks = (frame f, channel-half h); block: 64 threads (1 wave).
// Per chunk of CH_=16 steps: issue coalesced float4 loads of the NEXT chunk to
// registers, compute current chunk from LDS, then commit regs->LDS. HBM latency
// hides under compute + commit; per-step critical path is the ~40-cycle gate chain.
#define CH_ 16
__global__ __launch_bounds__(64) void sru_scan(const float* __restrict__ U, const float* __restrict__ mask,
                          const float* __restrict__ vf, const float* __restrict__ vr,
                          const float* __restrict__ bf, const float* __restrict__ br,
                          float* __restrict__ hout, int dir) {
  const int blk = blockIdx.x;   // 0..127
  const int f = blk >> 1;       // frame
  const int hh = blk & 1;       // channel half
  const int t = threadIdx.x;    // 0..63
  const int b = f >> 3;
  __shared__ float lds[2][CH_*256];
  __shared__ float msk[512];
  for (int i = t; i < 512; i += 64) msk[i] = mask[b*512 + i];
  const int d = hh*64 + t;      // channel within direction
  const float vfd = vf[d], vrd = vr[d], bfd = bf[d], brd = br[d];
  const size_t fbase = (size_t)f * 512;
  const int g = t >> 4, j = t & 15;  // loader role: gate g, float4 index j
  float4 stage[CH_];

  // prologue: chunk 0
  #pragma unroll
  for (int s = 0; s < CH_; s++) {
    int l = dir ? 511 - s : s;
    stage[s] = *(const float4*)(U + (fbase + l)*512 + g*128 + hh*64 + j*4);
  }
  #pragma unroll
  for (int s = 0; s < CH_; s++)
    *(float4*)&lds[0][s*256 + t*4] = stage[s];
  __syncthreads();

  float c = 0.f;
  for (int c0 = 0; c0 < 512; c0 += CH_) {
    const int buf = (c0 / CH_) & 1;
    const bool more = (c0 + CH_) < 512;
    if (more) {
      #pragma unroll
      for (int s = 0; s < CH_; s++) {
        int step = c0 + CH_ + s;
        int l = dir ? 511 - step : step;
        stage[s] = *(const float4*)(U + (fbase + l)*512 + g*128 + hh*64 + j*4);
      }
    }
    #pragma unroll
    for (int s = 0; s < CH_; s++) {
      const int step = c0 + s;
      const int l = dir ? 511 - step : step;
      const float u0 = lds[buf][s*256 +       t];
      const float u1 = lds[buf][s*256 +  64 + t];
      const float u2 = lds[buf][s*256 + 128 + t];
      const float u3 = lds[buf][s*256 + 192 + t];
      const float fg = 1.f/(1.f + __expf(-(u1 + vfd*c + bfd)));
      const float rg = 1.f/(1.f + __expf(-(u2 + vrd*c + brd)));
      float cn = fg*c + (1.f-fg)*u0;
      const float m = msk[l];
      if (m == 0.f) cn = c;
      const float h = (m == 0.f) ? 0.f : (rg*cn + (1.f-rg)*u3);
      c = cn;
      hout[(fbase + l)*256 + (size_t)dir*128 + d] = h;
    }
    if (more) {
      #pragma unroll
      for (int s = 0; s < CH_; s++)
        *(float4*)&lds[buf^1][s*256 + t*4] = stage[s];
    }
    __syncthreads();
  }
}

// ---------------- mean over 8 sign-frames ----------------
__global__ void mean_kernel(const float* __restrict__ h2, float* __restrict__ out) {
  int i = blockIdx.x*256 + threadIdx.x;   // 0..262143 (float4 units)
  int row = i >> 6;        // b*512 + l
  int c4  = i & 63;
  int b = row >> 9, l = row & 511;
  float ax=0.f, ay=0.f, az=0.f, aw=0.f;
  #pragma unroll
  for (int o=0;o<8;o++) {
    const float4* p = (const float4*)(h2 + ((size_t)((b*8+o)*512 + l))*256) + c4;
    float4 e = *p;
    ax += e.x; ay += e.y; az += e.z; aw += e.w;
  }
  float4 r; r.x = ax*0.125f; r.y = ay*0.125f; r.z = az*0.125f; r.w = aw*0.125f;
  ((float4*)out)[i] = r;
}

extern "C" void kernel_launch(void* const* d_in, const int* in_sizes, int n_in,
                              void* d_out, int out_size, void* d_ws, size_t ws_size,
                              hipStream_t stream) {
  const int*   seqs  = (const int*)d_in[0];
  const float* cords = (const float*)d_in[1];
  const float* mask  = (const float*)d_in[2];
  const float* emb   = (const float*)d_in[3];
  const float* Wq[2] = {(const float*)d_in[4],  (const float*)d_in[12]};
  const float* Wk[2] = {(const float*)d_in[5],  (const float*)d_in[13]};
  const float* Wv[2] = {(const float*)d_in[6],  (const float*)d_in[14]};
  const float* Wu[2] = {(const float*)d_in[7],  (const float*)d_in[15]};
  const float* vf[2] = {(const float*)d_in[8],  (const float*)d_in[16]};
  const float* vr[2] = {(const float*)d_in[9],  (const float*)d_in[17]};
  const float* bfp[2]= {(const float*)d_in[10], (const float*)d_in[18]};
  const float* brp[2]= {(const float*)d_in[11], (const float*)d_in[19]};

  float* ws   = (float*)d_ws;
  float* misc = ws;
  float* h0 = ws + 256;
  float* q  = h0 + (size_t)M_*DIN0_;
  float* k  = q  + (size_t)M_*128;
  float* v  = k  + (size_t)M_*128;
  float* SU = v  + (size_t)M_*128;     // 16,777,216 floats: S then U (per dir)
  float* h1 = SU + (size_t)M_*512;
  float* a  = k;   // k dead after qk^T
  float* h2 = h0;  // h0 dead after layer-0 q

  geom_kernel<<<8, 256, 0, stream>>>(cords, mask, misc);
  build_h0<<<M_/4, 256, 0, stream>>>(seqs, cords, mask, emb, misc, h0);

  const float scale = 0.08838834764831845f; // 1/sqrt(128)
  for (int layer = 0; layer < 2; ++layer) {
    const float* hin = layer ? h1 : h0;
    int Kdim = layer ? 256 : 259;
    float* hout = layer ? h2 : h1;
    gemm_nn<<<dim3(M_/64, 2), 256, 0, stream>>>(hin, Wq[layer], q, M_, 128, Kdim, Kdim, 128, 128);
    gemm_nn<<<dim3(M_/64, 2), 256, 0, stream>>>(q, Wk[layer], k, M_, 128, 128, 128, 128, 128);
    gemm_nn<<<dim3(M_/64, 2), 256, 0, stream>>>(q, Wv[layer], v, M_, 128, 128, 128, 128, 128);
    gemm_qkT<<<dim3(8,8,64), 256, 0, stream>>>(q, k, SU, mask, scale);
    softmax_rows<<<M_, 64, 0, stream>>>(SU);
    gemm_pv<<<dim3(8,2,64), 256, 0, stream>>>(SU, v, q, a);
    for (int dir = 0; dir < 2; ++dir) {
      gemm_nn<<<dim3(M_/64, 8), 256, 0, stream>>>(a, Wu[layer] + dir*512, SU,
                                                  M_, 512, 128, 128, 1024, 512);
      sru_scan<<<128, 64, 0, stream>>>(SU, mask, vf[layer]+dir*128, vr[layer]+dir*128,
                                       bfp[layer]+dir*128, brp[layer]+dir*128, hout, dir);
    }
  }
  mean_kernel<<<1024, 256, 0, stream>>>(h2, (float*)d_out);
}

// Round 3
// 1091.225 us; speedup vs baseline: 1.4019x; 1.1692x over previous
//
#include <hip/hip_runtime.h>
#include <hip/hip_bf16.h>
#include <math.h>

#define L_    512
#define F_    64
#define M_    (F_*L_)   // 32768
#define D2_   128
#define H_    256
#define DIN0_ 259

// ---------------- geometry: center + covariance + 3x3 eigh ----------------
__global__ void geom_kernel(const float* __restrict__ cords, const float* __restrict__ mask,
                            float* __restrict__ misc) {
  int b = blockIdx.x;
  int t = threadIdx.x;
  __shared__ float red[4][256];
  float sx=0.f, sy=0.f, sz=0.f, sm=0.f;
  for (int l = t; l < 512; l += 256) {
    float m = mask[b*512 + l];
    const float* X = cords + ((size_t)(b*512 + l)*4 + 1)*3;
    sx += X[0]*m; sy += X[1]*m; sz += X[2]*m; sm += m;
  }
  red[0][t]=sx; red[1][t]=sy; red[2][t]=sz; red[3][t]=sm;
  __syncthreads();
  for (int off=128; off>0; off>>=1) {
    if (t < off) { red[0][t]+=red[0][t+off]; red[1][t]+=red[1][t+off];
                   red[2][t]+=red[2][t+off]; red[3][t]+=red[3][t+off]; }
    __syncthreads();
  }
  float inv = 1.f/red[3][0];
  float cx = red[0][0]*inv, cy = red[1][0]*inv, cz = red[2][0]*inv;
  __syncthreads();
  __shared__ float red6[6][256];
  float c00=0,c01=0,c02=0,c11=0,c12=0,c22=0;
  for (int l = t; l < 512; l += 256) {
    float m = mask[b*512+l];
    const float* X = cords + ((size_t)(b*512+l)*4 + 1)*3;
    float x = X[0]-cx*m, y = X[1]-cy*m, z = X[2]-cz*m;
    c00+=x*x; c01+=x*y; c02+=x*z; c11+=y*y; c12+=y*z; c22+=z*z;
  }
  red6[0][t]=c00; red6[1][t]=c01; red6[2][t]=c02;
  red6[3][t]=c11; red6[4][t]=c12; red6[5][t]=c22;
  __syncthreads();
  for (int off=128; off>0; off>>=1) {
    if (t < off) for (int j=0;j<6;j++) red6[j][t]+=red6[j][t+off];
    __syncthreads();
  }
  if (t == 0) {
    double A[3][3], V[3][3];
    A[0][0]=red6[0][0]; A[0][1]=A[1][0]=red6[1][0]; A[0][2]=A[2][0]=red6[2][0];
    A[1][1]=red6[3][0]; A[1][2]=A[2][1]=red6[4][0]; A[2][2]=red6[5][0];
    for (int j=0;j<3;j++) for (int i=0;i<3;i++) V[j][i] = (i==j)?1.0:0.0;
    for (int sweep=0; sweep<10; ++sweep) {
      for (int p=0;p<2;p++) for (int q=p+1;q<3;q++) {
        double apq = A[p][q];
        if (fabs(apq) < 1e-18) continue;
        double app = A[p][p], aqq = A[q][q];
        double tau = (aqq - app) / (2.0*apq);
        double tt = (tau >= 0.0) ? 1.0/(tau + sqrt(1.0+tau*tau))
                                 : 1.0/(tau - sqrt(1.0+tau*tau));
        double cc = 1.0/sqrt(1.0+tt*tt), ss = tt*cc;
        A[p][p] = app - tt*apq;
        A[q][q] = aqq + tt*apq;
        A[p][q] = A[q][p] = 0.0;
        int r = 3 - p - q;
        double arp = A[r][p], arq = A[r][q];
        A[r][p] = A[p][r] = cc*arp - ss*arq;
        A[r][q] = A[q][r] = ss*arp + cc*arq;
        for (int rr2=0; rr2<3; ++rr2) {
          double vrp = V[rr2][p], vrq = V[rr2][q];
          V[rr2][p] = cc*vrp - ss*vrq;
          V[rr2][q] = ss*vrp + cc*vrq;
        }
      }
    }
    double w[3] = {A[0][0], A[1][1], A[2][2]};
    int idx[3] = {0,1,2};
    for (int i=0;i<2;i++) for (int j=0;j<2-i;j++)
      if (w[idx[j]] > w[idx[j+1]]) { int tmp=idx[j]; idx[j]=idx[j+1]; idx[j+1]=tmp; }
    for (int jj=0;jj<3;jj++) for (int ii=0;ii<3;ii++)
      misc[b*12 + jj*3 + ii] = (float)V[jj][idx[ii]];
    misc[b*12+9]=cx; misc[b*12+10]=cy; misc[b*12+11]=cz;
  }
}

// ---------------- build h0: [F, L, 259] = [hX(3) | emb(256)] ----------------
__global__ void build_h0(const int* __restrict__ seqs, const float* __restrict__ cords,
                         const float* __restrict__ mask, const float* __restrict__ emb,
                         const float* __restrict__ misc, float* __restrict__ h0) {
  int t = threadIdx.x;
  int r = blockIdx.x*4 + (t >> 6);
  int lane = t & 63;
  int f = r >> 9, l = r & 511;
  int b = f >> 3, o = f & 7;
  float* row = h0 + (size_t)r * DIN0_;
  if (lane == 0) {
    float m = mask[b*512 + l];
    const float* X = cords + ((size_t)(b*512 + l)*4 + 1)*3;
    const float* mb = misc + b*12;
    float x = X[0]-mb[9]*m, y = X[1]-mb[10]*m, z = X[2]-mb[11]*m;
    #pragma unroll
    for (int i=0;i<3;i++) {
      float sgn = ((o >> (2-i)) & 1) ? 1.f : -1.f;
      row[i] = sgn * (mb[0+i]*x + mb[3+i]*y + mb[6+i]*z);
    }
  }
  int s = seqs[b*512 + l];
  if (s < 0) s = 82;
  const float4 e4 = *((const float4*)(emb + (size_t)s*256) + lane);
  row[3 + lane*4 + 0] = e4.x;
  row[3 + lane*4 + 1] = e4.y;
  row[3 + lane*4 + 2] = e4.z;
  row[3 + lane*4 + 3] = e4.w;
}

// ---------------- permute Wu columns: wup[dir][k][d*4+g] = Wu[k][(dir*4+g)*128+d] --
__global__ void permute_wu(const float* __restrict__ Wu, float* __restrict__ wup) {
  int k = blockIdx.x;      // 0..127
  int dir = blockIdx.y;    // 0..1
  int n = threadIdx.x;     // 0..511
  int d = n >> 2, g = n & 3;
  wup[((size_t)dir*128 + k)*512 + n] = Wu[(size_t)k*1024 + (dir*4+g)*128 + d];
}

// ---------------- generic fp32 NN GEMM (M,N multiples of 64) ----------------
__global__ __launch_bounds__(256) void gemm_nn(const float* __restrict__ A, const float* __restrict__ B,
                                               float* __restrict__ C,
                                               int M, int N, int K, int lda, int ldb, int ldc) {
  __shared__ float As[32][68];
  __shared__ float Bs[32][64];
  const int bm = blockIdx.x * 64, bn = blockIdx.y * 64;
  const int t = threadIdx.x;
  const int tx = t & 15, ty = t >> 4;
  float acc[4][4] = {};
  for (int k0 = 0; k0 < K; k0 += 32) {
    #pragma unroll
    for (int i = 0; i < 8; i++) {
      int idx = t + i*256;
      int kk = idx & 31, m = idx >> 5;
      int gk = k0 + kk;
      As[kk][m] = (gk < K) ? A[(size_t)(bm + m)*lda + gk] : 0.f;
    }
    #pragma unroll
    for (int i = 0; i < 8; i++) {
      int idx = t + i*256;
      int n = idx & 63, kk = idx >> 6;
      int gk = k0 + kk;
      Bs[kk][n] = (gk < K) ? B[(size_t)gk*ldb + bn + n] : 0.f;
    }
    __syncthreads();
    #pragma unroll
    for (int kk = 0; kk < 32; kk++) {
      float4 a4 = *(const float4*)&As[kk][ty*4];
      float4 b4 = *(const float4*)&Bs[kk][tx*4];
      float av[4] = {a4.x,a4.y,a4.z,a4.w};
      float bv[4] = {b4.x,b4.y,b4.z,b4.w};
      #pragma unroll
      for (int i=0;i<4;i++)
        #pragma unroll
        for (int j=0;j<4;j++)
          acc[i][j] += av[i]*bv[j];
    }
    __syncthreads();
  }
  #pragma unroll
  for (int i=0;i<4;i++) {
    size_t crow = (size_t)(bm + ty*4 + i)*ldc + bn;
    #pragma unroll
    for (int j=0;j<4;j++)
      C[crow + tx*4 + j] = acc[i][j];
  }
}

// ---------------- batched S = q @ k^T * scale, masked ----------------
__global__ __launch_bounds__(256) void gemm_qkT(const float* __restrict__ q, const float* __restrict__ k,
                                                float* __restrict__ S, const float* __restrict__ mask,
                                                float scale) {
  const int f = blockIdx.z;
  const float* A  = q + (size_t)f*512*128;
  const float* Bm = k + (size_t)f*512*128;
  float* Cm = S + (size_t)f*512*512;
  const int bm = blockIdx.x*64, bn = blockIdx.y*64;
  const int t = threadIdx.x, tx = t & 15, ty = t >> 4;
  __shared__ float As[32][68];
  __shared__ float Bs[32][68];
  float acc[4][4] = {};
  for (int k0 = 0; k0 < 128; k0 += 32) {
    #pragma unroll
    for (int i = 0; i < 8; i++) {
      int idx = t + i*256;
      int kk = idx & 31, m = idx >> 5;
      As[kk][m] = A [(size_t)(bm+m)*128 + k0 + kk];
      Bs[kk][m] = Bm[(size_t)(bn+m)*128 + k0 + kk];
    }
    __syncthreads();
    #pragma unroll
    for (int kk = 0; kk < 32; kk++) {
      float4 a4 = *(const float4*)&As[kk][ty*4];
      float4 b4 = *(const float4*)&Bs[kk][tx*4];
      float av[4] = {a4.x,a4.y,a4.z,a4.w};
      float bv[4] = {b4.x,b4.y,b4.z,b4.w};
      #pragma unroll
      for (int i=0;i<4;i++)
        #pragma unroll
        for (int j=0;j<4;j++)
          acc[i][j] += av[i]*bv[j];
    }
    __syncthreads();
  }
  const float* mrow = mask + (f>>3)*512 + bn;
  #pragma unroll
  for (int i=0;i<4;i++) {
    size_t crow = (size_t)(bm + ty*4 + i)*512 + bn;
    #pragma unroll
    for (int j=0;j<4;j++) {
      float val = acc[i][j]*scale;
      if (mrow[tx*4+j] == 0.f) val = -1e9f;
      Cm[crow + tx*4 + j] = val;
    }
  }
}

// ---------------- row softmax over 512 ----------------
__global__ void softmax_rows(float* __restrict__ S) {
  size_t row = blockIdx.x;
  float* p = S + row*512;
  int t = threadIdx.x; // 64
  float v[8];
  float mx = -1e30f;
  #pragma unroll
  for (int i=0;i<8;i++) { v[i] = p[t + i*64]; mx = fmaxf(mx, v[i]); }
  #pragma unroll
  for (int off=32; off>0; off>>=1) mx = fmaxf(mx, __shfl_xor(mx, off));
  float sum = 0.f;
  #pragma unroll
  for (int i=0;i<8;i++) { v[i] = __expf(v[i]-mx); sum += v[i]; }
  #pragma unroll
  for (int off=32; off>0; off>>=1) sum += __shfl_xor(sum, off);
  float invs = 1.f/sum;
  #pragma unroll
  for (int i=0;i<8;i++) p[t + i*64] = v[i]*invs;
}

// ---------------- batched a = P @ v + q ----------------
__global__ __launch_bounds__(256) void gemm_pv(const float* __restrict__ S, const float* __restrict__ v,
                                               const float* __restrict__ q, float* __restrict__ a) {
  const int f = blockIdx.z;
  const float* A  = S + (size_t)f*512*512;
  const float* Bm = v + (size_t)f*512*128;
  const float* Rm = q + (size_t)f*512*128;
  float* Cm = a + (size_t)f*512*128;
  const int bm = blockIdx.x*64, bn = blockIdx.y*64;
  const int t = threadIdx.x, tx = t & 15, ty = t >> 4;
  __shared__ float As[32][68];
  __shared__ float Bs[32][64];
  float acc[4][4] = {};
  for (int k0 = 0; k0 < 512; k0 += 32) {
    #pragma unroll
    for (int i = 0; i < 8; i++) {
      int idx = t + i*256;
      int kk = idx & 31, m = idx >> 5;
      As[kk][m] = A[(size_t)(bm+m)*512 + k0 + kk];
    }
    #pragma unroll
    for (int i = 0; i < 8; i++) {
      int idx = t + i*256;
      int n = idx & 63, kk = idx >> 6;
      Bs[kk][n] = Bm[(size_t)(k0+kk)*128 + bn + n];
    }
    __syncthreads();
    #pragma unroll
    for (int kk = 0; kk < 32; kk++) {
      float4 a4 = *(const float4*)&As[kk][ty*4];
      float4 b4 = *(const float4*)&Bs[kk][tx*4];
      float av[4] = {a4.x,a4.y,a4.z,a4.w};
      float bv[4] = {b4.x,b4.y,b4.z,b4.w};
      #pragma unroll
      for (int i=0;i<4;i++)
        #pragma unroll
        for (int j=0;j<4;j++)
          acc[i][j] += av[i]*bv[j];
    }
    __syncthreads();
  }
  #pragma unroll
  for (int i=0;i<4;i++) {
    size_t crow = (size_t)(bm + ty*4 + i)*128 + bn;
    #pragma unroll
    for (int j=0;j<4;j++)
      Cm[crow + tx*4 + j] = acc[i][j] + Rm[crow + tx*4 + j];
  }
}

// ---------------- sequential SRU scan: register ring, float4 gates ----------------
// U' layout: [row=f*512+l][512] where column d*4+g = gate g of channel d.
// grid: 128 blocks = (frame, channel-half); 64 threads (1 wave).
// 4 register buffers x 8 steps (float4 each) = 3-chunk-deep HBM prefetch (~1100 cy).
// Loads of chunk c+3 are issued BEFORE chunk c's h-stores each iteration, so the
// vmcnt wait for a buffer never traps store-acks (in-order vmcnt retirement).
#define CH_ 8
#define LOADC(buf, ch) do { \
  int _c = (ch); \
  _Pragma("unroll") \
  for (int s = 0; s < CH_; s++) { \
    int stp = _c*CH_ + s; \
    int l = dirv ? 511 - stp : stp; \
    buf[s] = *(const float4*)(Ubase + (size_t)l*512); \
  } } while(0)

#define COMPC(buf, ch) do { \
  int _c = (ch); \
  float mk[CH_]; \
  _Pragma("unroll") \
  for (int s = 0; s < CH_; s++) { \
    int stp = _c*CH_ + s; \
    int l = dirv ? 511 - stp : stp; \
    mk[s] = msk[l]; \
  } \
  _Pragma("unroll") \
  for (int s = 0; s < CH_; s++) { \
    int stp = _c*CH_ + s; \
    int l = dirv ? 511 - stp : stp; \
    float4 u = buf[s]; \
    float xf = (u.y + bfd) + vfd*cstate; \
    float xr = (u.z + brd) + vrd*cstate; \
    float fg = 1.f/(1.f + __expf(-xf)); \
    float rg = 1.f/(1.f + __expf(-xr)); \
    float cn = fg*(cstate - u.x) + u.x; \
    if (mk[s] == 0.f) cn = cstate; \
    float h = (mk[s] == 0.f) ? 0.f : (rg*(cn - u.w) + u.w); \
    cstate = cn; \
    houtp[(size_t)l*256] = h; \
  } } while(0)

__global__ __launch_bounds__(64) void sru_scan(const float* __restrict__ U, const float* __restrict__ mask,
                          const float* __restrict__ vf, const float* __restrict__ vr,
                          const float* __restrict__ bf, const float* __restrict__ br,
                          float* __restrict__ hout, int dirv) {
  const int blk = blockIdx.x;   // 0..127
  const int f = blk >> 1;       // frame
  const int hh = blk & 1;       // channel half
  const int t = threadIdx.x;    // 0..63
  const int b = f >> 3;
  __shared__ float msk[512];
  for (int i = t; i < 512; i += 64) msk[i] = mask[b*512 + i];
  __syncthreads();
  const int d = hh*64 + t;      // channel within direction
  const float vfd = vf[d], vrd = vr[d], bfd = bf[d], brd = br[d];
  const size_t fbase = (size_t)f * 512;
  const float* Ubase = U + fbase*512 + d*4;
  float* houtp = hout + fbase*256 + (size_t)blockIdx.y*128 + d; // blockIdx.y = dir? no...
  houtp = hout + fbase*256 + (size_t)dirv*128 + d;

  float4 b0[CH_], b1[CH_], b2[CH_], b3[CH_];
  LOADC(b0, 0); LOADC(b1, 1); LOADC(b2, 2);
  float cstate = 0.f;
  for (int q4 = 0; q4 < 16; q4++) {
    const int base = q4*4;
    if (base + 3 < 64) LOADC(b3, base+3);
    COMPC(b0, base);
    if (base + 4 < 64) LOADC(b0, base+4);
    COMPC(b1, base+1);
    if (base + 5 < 64) LOADC(b1, base+5);
    COMPC(b2, base+2);
    if (base + 6 < 64) LOADC(b2, base+6);
    COMPC(b3, base+3);
  }
}

// ---------------- mean over 8 sign-frames ----------------
__global__ void mean_kernel(const float* __restrict__ h2, float* __restrict__ out) {
  int i = blockIdx.x*256 + threadIdx.x;   // 0..262143 (float4 units)
  int row = i >> 6;        // b*512 + l
  int c4  = i & 63;
  int b = row >> 9, l = row & 511;
  float ax=0.f, ay=0.f, az=0.f, aw=0.f;
  #pragma unroll
  for (int o=0;o<8;o++) {
    const float4* p = (const float4*)(h2 + ((size_t)((b*8+o)*512 + l))*256) + c4;
    float4 e = *p;
    ax += e.x; ay += e.y; az += e.z; aw += e.w;
  }
  float4 r; r.x = ax*0.125f; r.y = ay*0.125f; r.z = az*0.125f; r.w = aw*0.125f;
  ((float4*)out)[i] = r;
}

extern "C" void kernel_launch(void* const* d_in, const int* in_sizes, int n_in,
                              void* d_out, int out_size, void* d_ws, size_t ws_size,
                              hipStream_t stream) {
  const int*   seqs  = (const int*)d_in[0];
  const float* cords = (const float*)d_in[1];
  const float* mask  = (const float*)d_in[2];
  const float* emb   = (const float*)d_in[3];
  const float* Wq[2] = {(const float*)d_in[4],  (const float*)d_in[12]};
  const float* Wk[2] = {(const float*)d_in[5],  (const float*)d_in[13]};
  const float* Wv[2] = {(const float*)d_in[6],  (const float*)d_in[14]};
  const float* Wu[2] = {(const float*)d_in[7],  (const float*)d_in[15]};
  const float* vf[2] = {(const float*)d_in[8],  (const float*)d_in[16]};
  const float* vr[2] = {(const float*)d_in[9],  (const float*)d_in[17]};
  const float* bfp[2]= {(const float*)d_in[10], (const float*)d_in[18]};
  const float* brp[2]= {(const float*)d_in[11], (const float*)d_in[19]};

  float* ws   = (float*)d_ws;
  float* misc = ws;
  float* h0 = ws + 256;
  float* q  = h0 + (size_t)M_*DIN0_;
  float* k  = q  + (size_t)M_*128;
  float* v  = k  + (size_t)M_*128;
  float* SU = v  + (size_t)M_*128;     // 16,777,216 floats: S then U' (per dir)
  float* h1 = SU + (size_t)M_*512;
  float* wup = h1 + (size_t)M_*256;    // 2 x 128 x 512 permuted Wu
  float* a  = k;   // k dead after qk^T
  float* h2 = h0;  // h0 dead after layer-0 q

  geom_kernel<<<8, 256, 0, stream>>>(cords, mask, misc);
  build_h0<<<M_/4, 256, 0, stream>>>(seqs, cords, mask, emb, misc, h0);

  const float scale = 0.08838834764831845f; // 1/sqrt(128)
  for (int layer = 0; layer < 2; ++layer) {
    const float* hin = layer ? h1 : h0;
    int Kdim = layer ? 256 : 259;
    float* hout = layer ? h2 : h1;
    permute_wu<<<dim3(128,2), 512, 0, stream>>>(Wu[layer], wup);
    gemm_nn<<<dim3(M_/64, 2), 256, 0, stream>>>(hin, Wq[layer], q, M_, 128, Kdim, Kdim, 128, 128);
    gemm_nn<<<dim3(M_/64, 2), 256, 0, stream>>>(q, Wk[layer], k, M_, 128, 128, 128, 128, 128);
    gemm_nn<<<dim3(M_/64, 2), 256, 0, stream>>>(q, Wv[layer], v, M_, 128, 128, 128, 128, 128);
    gemm_qkT<<<dim3(8,8,64), 256, 0, stream>>>(q, k, SU, mask, scale);
    softmax_rows<<<M_, 64, 0, stream>>>(SU);
    gemm_pv<<<dim3(8,2,64), 256, 0, stream>>>(SU, v, q, a);
    for (int dir = 0; dir < 2; ++dir) {
      gemm_nn<<<dim3(M_/64, 8), 256, 0, stream>>>(a, wup + (size_t)dir*128*512, SU,
                                                  M_, 512, 128, 128, 512, 512);
      sru_scan<<<128, 64, 0, stream>>>(SU, mask, vf[layer]+dir*128, vr[layer]+dir*128,
                                       bfp[layer]+dir*128, brp[layer]+dir*128, hout, dir);
    }
  }
  mean_kernel<<<1024, 256, 0, stream>>>(h2, (float*)d_out);
}

// Round 4
// 721.995 us; speedup vs baseline: 2.1188x; 1.5114x over previous
//
#include <hip/hip_runtime.h>
#include <hip/hip_bf16.h>
#include <math.h>

#define L_    512
#define F_    64
#define M_    (F_*L_)   // 32768
#define D2_   128
#define H_    256

typedef unsigned short u16;
typedef __attribute__((ext_vector_type(8))) short s16x8;
typedef __attribute__((ext_vector_type(4))) float f32x4;

__device__ inline u16 bf_hi(float x) {
  union { float f; unsigned u; } v; v.f = x;
  unsigned r = v.u + 0x7fffu + ((v.u >> 16) & 1u);
  return (u16)(r >> 16);
}
__device__ inline float bf_to_f(u16 h) {
  union { float f; unsigned u; } v; v.u = ((unsigned)h) << 16; return v.f;
}
__device__ inline void split2(float x, u16& h, u16& l) {
  h = bf_hi(x);
  l = bf_hi(x - bf_to_f(h));   // exact residual (Sterbenz), bf16-rounded
}

// ---------------- geometry: center + covariance + 3x3 eigh ----------------
__global__ void geom_kernel(const float* __restrict__ cords, const float* __restrict__ mask,
                            float* __restrict__ misc) {
  int b = blockIdx.x;
  int t = threadIdx.x;
  __shared__ float red[4][256];
  float sx=0.f, sy=0.f, sz=0.f, sm=0.f;
  for (int l = t; l < 512; l += 256) {
    float m = mask[b*512 + l];
    const float* X = cords + ((size_t)(b*512 + l)*4 + 1)*3;
    sx += X[0]*m; sy += X[1]*m; sz += X[2]*m; sm += m;
  }
  red[0][t]=sx; red[1][t]=sy; red[2][t]=sz; red[3][t]=sm;
  __syncthreads();
  for (int off=128; off>0; off>>=1) {
    if (t < off) { red[0][t]+=red[0][t+off]; red[1][t]+=red[1][t+off];
                   red[2][t]+=red[2][t+off]; red[3][t]+=red[3][t+off]; }
    __syncthreads();
  }
  float inv = 1.f/red[3][0];
  float cx = red[0][0]*inv, cy = red[1][0]*inv, cz = red[2][0]*inv;
  __syncthreads();
  __shared__ float red6[6][256];
  float c00=0,c01=0,c02=0,c11=0,c12=0,c22=0;
  for (int l = t; l < 512; l += 256) {
    float m = mask[b*512+l];
    const float* X = cords + ((size_t)(b*512+l)*4 + 1)*3;
    float x = X[0]-cx*m, y = X[1]-cy*m, z = X[2]-cz*m;
    c00+=x*x; c01+=x*y; c02+=x*z; c11+=y*y; c12+=y*z; c22+=z*z;
  }
  red6[0][t]=c00; red6[1][t]=c01; red6[2][t]=c02;
  red6[3][t]=c11; red6[4][t]=c12; red6[5][t]=c22;
  __syncthreads();
  for (int off=128; off>0; off>>=1) {
    if (t < off) for (int j=0;j<6;j++) red6[j][t]+=red6[j][t+off];
    __syncthreads();
  }
  if (t == 0) {
    double A[3][3], V[3][3];
    A[0][0]=red6[0][0]; A[0][1]=A[1][0]=red6[1][0]; A[0][2]=A[2][0]=red6[2][0];
    A[1][1]=red6[3][0]; A[1][2]=A[2][1]=red6[4][0]; A[2][2]=red6[5][0];
    for (int j=0;j<3;j++) for (int i=0;i<3;i++) V[j][i] = (i==j)?1.0:0.0;
    for (int sweep=0; sweep<10; ++sweep) {
      for (int p=0;p<2;p++) for (int q=p+1;q<3;q++) {
        double apq = A[p][q];
        if (fabs(apq) < 1e-18) continue;
        double app = A[p][p], aqq = A[q][q];
        double tau = (aqq - app) / (2.0*apq);
        double tt = (tau >= 0.0) ? 1.0/(tau + sqrt(1.0+tau*tau))
                                 : 1.0/(tau - sqrt(1.0+tau*tau));
        double cc = 1.0/sqrt(1.0+tt*tt), ss = tt*cc;
        A[p][p] = app - tt*apq;
        A[q][q] = aqq + tt*apq;
        A[p][q] = A[q][p] = 0.0;
        int r = 3 - p - q;
        double arp = A[r][p], arq = A[r][q];
        A[r][p] = A[p][r] = cc*arp - ss*arq;
        A[r][q] = A[q][r] = ss*arp + cc*arq;
        for (int rr2=0; rr2<3; ++rr2) {
          double vrp = V[rr2][p], vrq = V[rr2][q];
          V[rr2][p] = cc*vrp - ss*vrq;
          V[rr2][q] = ss*vrp + cc*vrq;
        }
      }
    }
    double w[3] = {A[0][0], A[1][1], A[2][2]};
    int idx[3] = {0,1,2};
    for (int i=0;i<2;i++) for (int j=0;j<2-i;j++)
      if (w[idx[j]] > w[idx[j+1]]) { int tmp=idx[j]; idx[j]=idx[j+1]; idx[j+1]=tmp; }
    for (int jj=0;jj<3;jj++) for (int ii=0;ii<3;ii++)
      misc[b*12 + jj*3 + ii] = (float)V[jj][idx[ii]];
    misc[b*12+9]=cx; misc[b*12+10]=cy; misc[b*12+11]=cz;
  }
}

// ---------------- build h0 pairs: [F*L][288] = [hX(3) | emb(256) | 0-pad(29)] ----
__global__ void build_h0(const int* __restrict__ seqs, const float* __restrict__ cords,
                         const float* __restrict__ mask, const float* __restrict__ emb,
                         const float* __restrict__ misc,
                         u16* __restrict__ h0h, u16* __restrict__ h0l) {
  int t = threadIdx.x;
  int r = blockIdx.x*4 + (t >> 6);
  int lane = t & 63;
  int f = r >> 9, l = r & 511;
  int b = f >> 3, o = f & 7;
  u16* rh = h0h + (size_t)r * 288;
  u16* rl = h0l + (size_t)r * 288;
  if (lane == 0) {
    float m = mask[b*512 + l];
    const float* X = cords + ((size_t)(b*512 + l)*4 + 1)*3;
    const float* mb = misc + b*12;
    float x = X[0]-mb[9]*m, y = X[1]-mb[10]*m, z = X[2]-mb[11]*m;
    #pragma unroll
    for (int i=0;i<3;i++) {
      float sgn = ((o >> (2-i)) & 1) ? 1.f : -1.f;
      float val = sgn * (mb[0+i]*x + mb[3+i]*y + mb[6+i]*z);
      u16 h,lo; split2(val,h,lo); rh[i]=h; rl[i]=lo;
    }
  }
  if (lane < 29) { rh[259+lane] = 0; rl[259+lane] = 0; }
  int s = seqs[b*512 + l];
  if (s < 0) s = 82;
  const float4 e4 = *((const float4*)(emb + (size_t)s*256) + lane);
  float ev[4] = {e4.x, e4.y, e4.z, e4.w};
  #pragma unroll
  for (int i=0;i<4;i++) {
    u16 h,lo; split2(ev[i],h,lo);
    rh[3 + lane*4 + i] = h; rl[3 + lane*4 + i] = lo;
  }
}

// ---------------- weight prep: transpose + split, zero-pad K ----------------
__global__ void prep_wT(const float* __restrict__ W, u16* __restrict__ Th, u16* __restrict__ Tl,
                        int K, int KP) {
  int n = blockIdx.x;           // 0..127 (output row)
  for (int k = threadIdx.x; k < KP; k += 128) {
    float x = (k < K) ? W[(size_t)k*128 + n] : 0.f;
    u16 h,l; split2(x,h,l);
    Th[(size_t)n*KP + k] = h; Tl[(size_t)n*KP + k] = l;
  }
}

// wuT[(dir*512 + d*4+g)][k] = Wu[k][(dir*4+g)*128 + d]
__global__ void prep_wu(const float* __restrict__ Wu, u16* __restrict__ Th, u16* __restrict__ Tl) {
  int n = blockIdx.x;    // 0..511
  int dir = blockIdx.y;  // 0..1
  int k = threadIdx.x;   // 0..127
  int d = n >> 2, g = n & 3;
  float x = Wu[(size_t)k*1024 + (dir*4+g)*128 + d];
  u16 h,l; split2(x,h,l);
  size_t o = ((size_t)dir*512 + n)*128 + k;
  Th[o]=h; Tl[o]=l;
}

// ---------------- split-bf16 MFMA GEMM ----------------
// C[m][n] = sum_k A[m][k]*B[n][k]  (both operands [row][k] with k-contiguous pairs)
// 128x128 block tile, 4 waves (64x64 each), 16x16x32 bf16 MFMA, 3 MFMAs/frag (hi*hi+hi*lo+lo*hi).
// EPI: 0 = write split pairs Ch/Cl
//      1 = write V^T pairs (transposed per-frame)
//      2 = qkT: scale+mask -> fp32 Cf
//      3 = pv : + residual(rh,rl) -> split pairs
//      4 = write fp32 Cf
template<int EPI>
__global__ __launch_bounds__(256) void gemm_bb(
    const u16* __restrict__ Ah, const u16* __restrict__ Al,
    const u16* __restrict__ Bh, const u16* __restrict__ Bl,
    int KP, int lda, int ldb,
    long aBatch, long bBatch, long cBatch,
    u16* __restrict__ Ch, u16* __restrict__ Cl, int ldc,
    float* __restrict__ Cf,
    const u16* __restrict__ rh, const u16* __restrict__ rl,
    const float* __restrict__ maskp, float scale)
{
  __shared__ u16 As[2][128][40];
  __shared__ u16 Bs[2][128][40];
  const int t = threadIdx.x;
  const int z = blockIdx.z;
  const int bm = blockIdx.x * 128, bn = blockIdx.y * 128;
  Ah += (size_t)z * aBatch; Al += (size_t)z * aBatch;
  Bh += (size_t)z * bBatch; Bl += (size_t)z * bBatch;

  const int lane = t & 63;
  const int w = t >> 6, wr = w >> 1, wc = w & 1;
  const int fr = lane & 15, g = lane >> 4;

  f32x4 acc[4][4] = {};

  for (int k0 = 0; k0 < KP; k0 += 32) {
    #pragma unroll
    for (int cc = 0; cc < 2; cc++) {
      int c = t + cc*256;
      int m = c >> 2, sub = c & 3;
      const size_t ga = (size_t)(bm + m)*lda + k0 + sub*8;
      const size_t gb = (size_t)(bn + m)*ldb + k0 + sub*8;
      *(int4*)&As[0][m][sub*8] = *(const int4*)(Ah + ga);
      *(int4*)&As[1][m][sub*8] = *(const int4*)(Al + ga);
      *(int4*)&Bs[0][m][sub*8] = *(const int4*)(Bh + gb);
      *(int4*)&Bs[1][m][sub*8] = *(const int4*)(Bl + gb);
    }
    __syncthreads();
    s16x8 af[4][2], bfr[4][2];
    #pragma unroll
    for (int i = 0; i < 4; i++) {
      af[i][0]  = *(const s16x8*)&As[0][wr*64 + i*16 + fr][g*8];
      af[i][1]  = *(const s16x8*)&As[1][wr*64 + i*16 + fr][g*8];
      bfr[i][0] = *(const s16x8*)&Bs[0][wc*64 + i*16 + fr][g*8];
      bfr[i][1] = *(const s16x8*)&Bs[1][wc*64 + i*16 + fr][g*8];
    }
    #pragma unroll
    for (int mi = 0; mi < 4; mi++)
      #pragma unroll
      for (int nj = 0; nj < 4; nj++)
        acc[mi][nj] = __builtin_amdgcn_mfma_f32_16x16x32_bf16(af[mi][0], bfr[nj][0], acc[mi][nj], 0,0,0);
    #pragma unroll
    for (int mi = 0; mi < 4; mi++)
      #pragma unroll
      for (int nj = 0; nj < 4; nj++)
        acc[mi][nj] = __builtin_amdgcn_mfma_f32_16x16x32_bf16(af[mi][0], bfr[nj][1], acc[mi][nj], 0,0,0);
    #pragma unroll
    for (int mi = 0; mi < 4; mi++)
      #pragma unroll
      for (int nj = 0; nj < 4; nj++)
        acc[mi][nj] = __builtin_amdgcn_mfma_f32_16x16x32_bf16(af[mi][1], bfr[nj][0], acc[mi][nj], 0,0,0);
    __syncthreads();
  }

  const int rbase = bm + wr*64, nbase = bn + wc*64;
  #pragma unroll
  for (int mi = 0; mi < 4; mi++) {
    #pragma unroll
    for (int nj = 0; nj < 4; nj++) {
      #pragma unroll
      for (int rg = 0; rg < 4; rg++) {
        int r = rbase + mi*16 + g*4 + rg;
        int n = nbase + nj*16 + fr;
        float val = acc[mi][nj][rg];
        if (EPI == 0) {
          size_t o = (size_t)r*ldc + n;
          u16 h,l; split2(val,h,l);
          Ch[o]=h; Cl[o]=l;
        } else if (EPI == 1) {      // V^T pairs: [frame][n][l]
          size_t o = ((size_t)(r >> 9)*128 + n)*512 + (r & 511);
          u16 h,l; split2(val,h,l);
          Ch[o]=h; Cl[o]=l;
        } else if (EPI == 2) {      // qkT -> fp32 S with scale+mask
          float vv = val * scale;
          if (maskp[(z>>3)*512 + n] == 0.f) vv = -1e9f;
          Cf[(size_t)z*cBatch + (size_t)r*ldc + n] = vv;
        } else if (EPI == 3) {      // pv: + q residual -> pairs
          size_t o = (size_t)z*cBatch + (size_t)r*ldc + n;
          float vv = val + (bf_to_f(rh[o]) + bf_to_f(rl[o]));
          u16 h,l; split2(vv,h,l);
          Ch[o]=h; Cl[o]=l;
        } else {                    // 4: fp32 out
          Cf[(size_t)r*ldc + n] = val;
        }
      }
    }
  }
}

// ---------------- row softmax over 512, fp32 in -> split-bf16 pairs in place ----
__global__ void softmax_split(float* __restrict__ S) {
  size_t row = blockIdx.x;
  float* p = S + row*512;
  u16* ph = (u16*)p;        // hi plane: first 1024B of row
  u16* pl = ph + 512;       // lo plane: second 1024B
  int t = threadIdx.x; // 64
  float v[8];
  float mx = -1e30f;
  #pragma unroll
  for (int i=0;i<8;i++) { v[i] = p[t + i*64]; mx = fmaxf(mx, v[i]); }
  #pragma unroll
  for (int off=32; off>0; off>>=1) mx = fmaxf(mx, __shfl_xor(mx, off));
  float sum = 0.f;
  #pragma unroll
  for (int i=0;i<8;i++) { v[i] = __expf(v[i]-mx); sum += v[i]; }
  #pragma unroll
  for (int off=32; off>0; off>>=1) sum += __shfl_xor(sum, off);
  float invs = 1.f/sum;
  #pragma unroll
  for (int i=0;i<8;i++) {
    float x = v[i]*invs;
    u16 h,l; split2(x,h,l);
    ph[t + i*64] = h; pl[t + i*64] = l;
  }
}

// ---------------- sequential SRU scan: register ring, float4 gates ----------------
#define CH_ 8
#define LOADC(buf, ch) do { \
  int _c = (ch); \
  _Pragma("unroll") \
  for (int s = 0; s < CH_; s++) { \
    int stp = _c*CH_ + s; \
    int l = dirv ? 511 - stp : stp; \
    buf[s] = *(const float4*)(Ubase + (size_t)l*512); \
  } } while(0)

#define COMPC(buf, ch) do { \
  int _c = (ch); \
  float mk[CH_]; \
  _Pragma("unroll") \
  for (int s = 0; s < CH_; s++) { \
    int stp = _c*CH_ + s; \
    int l = dirv ? 511 - stp : stp; \
    mk[s] = msk[l]; \
  } \
  _Pragma("unroll") \
  for (int s = 0; s < CH_; s++) { \
    int stp = _c*CH_ + s; \
    int l = dirv ? 511 - stp : stp; \
    float4 u = buf[s]; \
    float xf = (u.y + bfd) + vfd*cstate; \
    float xr = (u.z + brd) + vrd*cstate; \
    float fg = 1.f/(1.f + __expf(-xf)); \
    float rg = 1.f/(1.f + __expf(-xr)); \
    float cn = fg*(cstate - u.x) + u.x; \
    if (mk[s] == 0.f) cn = cstate; \
    float h = (mk[s] == 0.f) ? 0.f : (rg*(cn - u.w) + u.w); \
    cstate = cn; \
    houtp[(size_t)l*256] = h; \
    u16 sh, sl; split2(h, sh, sl); \
    hpph[(size_t)l*256] = sh; \
    hppl[(size_t)l*256] = sl; \
  } } while(0)

__global__ __launch_bounds__(64) void sru_scan(const float* __restrict__ U, const float* __restrict__ mask,
                          const float* __restrict__ vf, const float* __restrict__ vr,
                          const float* __restrict__ bf, const float* __restrict__ br,
                          float* __restrict__ hout, u16* __restrict__ hph, u16* __restrict__ hpl,
                          int dirv) {
  const int blk = blockIdx.x;   // 0..127
  const int f = blk >> 1;       // frame
  const int hh = blk & 1;       // channel half
  const int t = threadIdx.x;    // 0..63
  const int b = f >> 3;
  __shared__ float msk[512];
  for (int i = t; i < 512; i += 64) msk[i] = mask[b*512 + i];
  __syncthreads();
  const int d = hh*64 + t;      // channel within direction
  const float vfd = vf[d], vrd = vr[d], bfd = bf[d], brd = br[d];
  const size_t fbase = (size_t)f * 512;
  const float* Ubase = U + fbase*512 + d*4;
  float* houtp = hout + fbase*256 + (size_t)dirv*128 + d;
  u16* hpph = hph + fbase*256 + (size_t)dirv*128 + d;
  u16* hppl = hpl + fbase*256 + (size_t)dirv*128 + d;

  float4 b0[CH_], b1[CH_], b2[CH_], b3[CH_];
  LOADC(b0, 0); LOADC(b1, 1); LOADC(b2, 2);
  float cstate = 0.f;
  for (int q4 = 0; q4 < 16; q4++) {
    const int base = q4*4;
    if (base + 3 < 64) LOADC(b3, base+3);
    COMPC(b0, base);
    if (base + 4 < 64) LOADC(b0, base+4);
    COMPC(b1, base+1);
    if (base + 5 < 64) LOADC(b1, base+5);
    COMPC(b2, base+2);
    if (base + 6 < 64) LOADC(b2, base+6);
    COMPC(b3, base+3);
  }
}

// ---------------- mean over 8 sign-frames ----------------
__global__ void mean_kernel(const float* __restrict__ h2, float* __restrict__ out) {
  int i = blockIdx.x*256 + threadIdx.x;   // float4 units
  int row = i >> 6;        // b*512 + l
  int c4  = i & 63;
  int b = row >> 9, l = row & 511;
  float ax=0.f, ay=0.f, az=0.f, aw=0.f;
  #pragma unroll
  for (int o=0;o<8;o++) {
    const float4* p = (const float4*)(h2 + ((size_t)((b*8+o)*512 + l))*256) + c4;
    float4 e = *p;
    ax += e.x; ay += e.y; az += e.z; aw += e.w;
  }
  float4 r; r.x = ax*0.125f; r.y = ay*0.125f; r.z = az*0.125f; r.w = aw*0.125f;
  ((float4*)out)[i] = r;
}

extern "C" void kernel_launch(void* const* d_in, const int* in_sizes, int n_in,
                              void* d_out, int out_size, void* d_ws, size_t ws_size,
                              hipStream_t stream) {
  const int*   seqs  = (const int*)d_in[0];
  const float* cords = (const float*)d_in[1];
  const float* mask  = (const float*)d_in[2];
  const float* emb   = (const float*)d_in[3];
  const float* Wq[2] = {(const float*)d_in[4],  (const float*)d_in[12]};
  const float* Wk[2] = {(const float*)d_in[5],  (const float*)d_in[13]};
  const float* Wv[2] = {(const float*)d_in[6],  (const float*)d_in[14]};
  const float* Wu[2] = {(const float*)d_in[7],  (const float*)d_in[15]};
  const float* vf[2] = {(const float*)d_in[8],  (const float*)d_in[16]};
  const float* vr[2] = {(const float*)d_in[9],  (const float*)d_in[17]};
  const float* bfp[2]= {(const float*)d_in[10], (const float*)d_in[18]};
  const float* brp[2]= {(const float*)d_in[11], (const float*)d_in[19]};

  char* base = (char*)d_ws;
  float* misc = (float*)base;                                   // 512 B
  u16* h0p_h = (u16*)(base + 512);                              // 32768*288*2 = 18,874,368
  u16* h0p_l = h0p_h + (size_t)M_*288;
  float* h_f32 = (float*)h0p_h;                                 // overlay (33.5MB <= 37.7MB), used after h0p dead
  u16* q_h = (u16*)(base + 512 + 2*(size_t)M_*288*2);
  u16* q_l = q_h + (size_t)M_*128;
  u16* k_h = q_l + (size_t)M_*128;
  u16* k_l = k_h + (size_t)M_*128;
  u16* a_h = k_h;  u16* a_l = k_l;                              // overlay (k dead after qkT)
  float* S  = (float*)(k_l + (size_t)M_*128);                   // 64MB: S -> P pairs -> U'
  float* Uprime = S;
  u16* hp_h = (u16*)((char*)S + (size_t)M_*512*4);
  u16* hp_l = hp_h + (size_t)M_*256;
  u16* vT_h = hp_h;  u16* vT_l = hp_l;                          // overlay (vT dead before scan writes hp)
  u16* wqT_h = hp_l + (size_t)M_*256;
  u16* wqT_l = wqT_h + 128*288;
  u16* wkT_h = wqT_l + 128*288;
  u16* wkT_l = wkT_h + 128*128;
  u16* wvT_h = wkT_l + 128*128;
  u16* wvT_l = wvT_h + 128*128;
  u16* wuT_h = wvT_l + 128*128;
  u16* wuT_l = wuT_h + 1024*128;

  geom_kernel<<<8, 256, 0, stream>>>(cords, mask, misc);
  build_h0<<<M_/4, 256, 0, stream>>>(seqs, cords, mask, emb, misc, h0p_h, h0p_l);

  const float scale = 0.08838834764831845f; // 1/sqrt(128)
  for (int layer = 0; layer < 2; ++layer) {
    const u16* Ah_in = layer ? hp_h : h0p_h;
    const u16* Al_in = layer ? hp_l : h0p_l;
    const int  Kq    = layer ? 256 : 259;
    const int  KPq   = layer ? 256 : 288;

    prep_wT<<<128, 128, 0, stream>>>(Wq[layer], wqT_h, wqT_l, Kq, KPq);
    prep_wT<<<128, 128, 0, stream>>>(Wk[layer], wkT_h, wkT_l, 128, 128);
    prep_wT<<<128, 128, 0, stream>>>(Wv[layer], wvT_h, wvT_l, 128, 128);
    prep_wu<<<dim3(512,2), 128, 0, stream>>>(Wu[layer], wuT_h, wuT_l);

    // q = hin @ Wq  -> pairs
    gemm_bb<0><<<dim3(256,1,1), 256, 0, stream>>>(Ah_in, Al_in, wqT_h, wqT_l,
        KPq, KPq, KPq, 0,0,0, q_h, q_l, 128, nullptr, nullptr, nullptr, nullptr, 0.f);
    // k = q @ Wk -> pairs
    gemm_bb<0><<<dim3(256,1,1), 256, 0, stream>>>(q_h, q_l, wkT_h, wkT_l,
        128, 128, 128, 0,0,0, k_h, k_l, 128, nullptr, nullptr, nullptr, nullptr, 0.f);
    // v = q @ Wv -> V^T pairs
    gemm_bb<1><<<dim3(256,1,1), 256, 0, stream>>>(q_h, q_l, wvT_h, wvT_l,
        128, 128, 128, 0,0,0, vT_h, vT_l, 0, nullptr, nullptr, nullptr, nullptr, 0.f);
    // S = q k^T * scale (masked)
    gemm_bb<2><<<dim3(4,4,64), 256, 0, stream>>>(q_h, q_l, k_h, k_l,
        128, 128, 128, 512*128, 512*128, 512*512, nullptr, nullptr, 512, S,
        nullptr, nullptr, mask, scale);
    // P = softmax(S) -> pairs (in place)
    softmax_split<<<M_, 64, 0, stream>>>(S);
    // a = P @ v + q -> pairs
    gemm_bb<3><<<dim3(4,1,64), 256, 0, stream>>>((const u16*)S, (const u16*)S + 512, vT_h, vT_l,
        512, 1024, 512, 512*1024, 128*512, 512*128, a_h, a_l, 128, nullptr,
        q_h, q_l, nullptr, 0.f);
    for (int dir = 0; dir < 2; ++dir) {
      // U' = a @ WuT(dir) -> fp32 (gate-interleaved columns d*4+g)
      gemm_bb<4><<<dim3(256,4,1), 256, 0, stream>>>(a_h, a_l,
          wuT_h + (size_t)dir*512*128, wuT_l + (size_t)dir*512*128,
          128, 128, 128, 0,0,0, nullptr, nullptr, 512, Uprime,
          nullptr, nullptr, nullptr, 0.f);
      sru_scan<<<128, 64, 0, stream>>>(Uprime, mask, vf[layer]+dir*128, vr[layer]+dir*128,
                                       bfp[layer]+dir*128, brp[layer]+dir*128,
                                       h_f32, hp_h, hp_l, dir);
    }
  }
  mean_kernel<<<1024, 256, 0, stream>>>(h_f32, (float*)d_out);
}

// Round 5
// 684.535 us; speedup vs baseline: 2.2348x; 1.0547x over previous
//
#include <hip/hip_runtime.h>
#include <hip/hip_bf16.h>
#include <math.h>

#define L_    512
#define F_    64
#define M_    (F_*L_)   // 32768
#define D2_   128
#define H_    256

typedef unsigned short u16;
typedef __attribute__((ext_vector_type(8))) short s16x8;
typedef __attribute__((ext_vector_type(4))) float f32x4;

__device__ inline u16 bf_hi(float x) {
  union { float f; unsigned u; } v; v.f = x;
  unsigned r = v.u + 0x7fffu + ((v.u >> 16) & 1u);
  return (u16)(r >> 16);
}
__device__ inline float bf_to_f(u16 h) {
  union { float f; unsigned u; } v; v.u = ((unsigned)h) << 16; return v.f;
}
__device__ inline void split2(float x, u16& h, u16& l) {
  h = bf_hi(x);
  l = bf_hi(x - bf_to_f(h));   // exact residual (Sterbenz), bf16-rounded
}

// ---------------- geometry: center + covariance + 3x3 eigh ----------------
__global__ void geom_kernel(const float* __restrict__ cords, const float* __restrict__ mask,
                            float* __restrict__ misc) {
  int b = blockIdx.x;
  int t = threadIdx.x;
  __shared__ float red[4][256];
  float sx=0.f, sy=0.f, sz=0.f, sm=0.f;
  for (int l = t; l < 512; l += 256) {
    float m = mask[b*512 + l];
    const float* X = cords + ((size_t)(b*512 + l)*4 + 1)*3;
    sx += X[0]*m; sy += X[1]*m; sz += X[2]*m; sm += m;
  }
  red[0][t]=sx; red[1][t]=sy; red[2][t]=sz; red[3][t]=sm;
  __syncthreads();
  for (int off=128; off>0; off>>=1) {
    if (t < off) { red[0][t]+=red[0][t+off]; red[1][t]+=red[1][t+off];
                   red[2][t]+=red[2][t+off]; red[3][t]+=red[3][t+off]; }
    __syncthreads();
  }
  float inv = 1.f/red[3][0];
  float cx = red[0][0]*inv, cy = red[1][0]*inv, cz = red[2][0]*inv;
  __syncthreads();
  __shared__ float red6[6][256];
  float c00=0,c01=0,c02=0,c11=0,c12=0,c22=0;
  for (int l = t; l < 512; l += 256) {
    float m = mask[b*512+l];
    const float* X = cords + ((size_t)(b*512+l)*4 + 1)*3;
    float x = X[0]-cx*m, y = X[1]-cy*m, z = X[2]-cz*m;
    c00+=x*x; c01+=x*y; c02+=x*z; c11+=y*y; c12+=y*z; c22+=z*z;
  }
  red6[0][t]=c00; red6[1][t]=c01; red6[2][t]=c02;
  red6[3][t]=c11; red6[4][t]=c12; red6[5][t]=c22;
  __syncthreads();
  for (int off=128; off>0; off>>=1) {
    if (t < off) for (int j=0;j<6;j++) red6[j][t]+=red6[j][t+off];
    __syncthreads();
  }
  if (t == 0) {
    double A[3][3], V[3][3];
    A[0][0]=red6[0][0]; A[0][1]=A[1][0]=red6[1][0]; A[0][2]=A[2][0]=red6[2][0];
    A[1][1]=red6[3][0]; A[1][2]=A[2][1]=red6[4][0]; A[2][2]=red6[5][0];
    for (int j=0;j<3;j++) for (int i=0;i<3;i++) V[j][i] = (i==j)?1.0:0.0;
    for (int sweep=0; sweep<10; ++sweep) {
      for (int p=0;p<2;p++) for (int q=p+1;q<3;q++) {
        double apq = A[p][q];
        if (fabs(apq) < 1e-18) continue;
        double app = A[p][p], aqq = A[q][q];
        double tau = (aqq - app) / (2.0*apq);
        double tt = (tau >= 0.0) ? 1.0/(tau + sqrt(1.0+tau*tau))
                                 : 1.0/(tau - sqrt(1.0+tau*tau));
        double cc = 1.0/sqrt(1.0+tt*tt), ss = tt*cc;
        A[p][p] = app - tt*apq;
        A[q][q] = aqq + tt*apq;
        A[p][q] = A[q][p] = 0.0;
        int r = 3 - p - q;
        double arp = A[r][p], arq = A[r][q];
        A[r][p] = A[p][r] = cc*arp - ss*arq;
        A[r][q] = A[q][r] = ss*arp + cc*arq;
        for (int rr2=0; rr2<3; ++rr2) {
          double vrp = V[rr2][p], vrq = V[rr2][q];
          V[rr2][p] = cc*vrp - ss*vrq;
          V[rr2][q] = ss*vrp + cc*vrq;
        }
      }
    }
    double w[3] = {A[0][0], A[1][1], A[2][2]};
    int idx[3] = {0,1,2};
    for (int i=0;i<2;i++) for (int j=0;j<2-i;j++)
      if (w[idx[j]] > w[idx[j+1]]) { int tmp=idx[j]; idx[j]=idx[j+1]; idx[j+1]=tmp; }
    for (int jj=0;jj<3;jj++) for (int ii=0;ii<3;ii++)
      misc[b*12 + jj*3 + ii] = (float)V[jj][idx[ii]];
    misc[b*12+9]=cx; misc[b*12+10]=cy; misc[b*12+11]=cz;
  }
}

// ---------------- build h0 pairs: [F*L][288] = [hX(3) | emb(256) | 0-pad(29)] ----
__global__ void build_h0(const int* __restrict__ seqs, const float* __restrict__ cords,
                         const float* __restrict__ mask, const float* __restrict__ emb,
                         const float* __restrict__ misc,
                         u16* __restrict__ h0h, u16* __restrict__ h0l) {
  int t = threadIdx.x;
  int r = blockIdx.x*4 + (t >> 6);
  int lane = t & 63;
  int f = r >> 9, l = r & 511;
  int b = f >> 3, o = f & 7;
  u16* rh = h0h + (size_t)r * 288;
  u16* rl = h0l + (size_t)r * 288;
  if (lane == 0) {
    float m = mask[b*512 + l];
    const float* X = cords + ((size_t)(b*512 + l)*4 + 1)*3;
    const float* mb = misc + b*12;
    float x = X[0]-mb[9]*m, y = X[1]-mb[10]*m, z = X[2]-mb[11]*m;
    #pragma unroll
    for (int i=0;i<3;i++) {
      float sgn = ((o >> (2-i)) & 1) ? 1.f : -1.f;
      float val = sgn * (mb[0+i]*x + mb[3+i]*y + mb[6+i]*z);
      u16 h,lo; split2(val,h,lo); rh[i]=h; rl[i]=lo;
    }
  }
  if (lane < 29) { rh[259+lane] = 0; rl[259+lane] = 0; }
  int s = seqs[b*512 + l];
  if (s < 0) s = 82;
  const float4 e4 = *((const float4*)(emb + (size_t)s*256) + lane);
  float ev[4] = {e4.x, e4.y, e4.z, e4.w};
  #pragma unroll
  for (int i=0;i<4;i++) {
    u16 h,lo; split2(ev[i],h,lo);
    rh[3 + lane*4 + i] = h; rl[3 + lane*4 + i] = lo;
  }
}

// ---------------- weight prep: transpose + split, zero-pad K ----------------
__global__ void prep_wT(const float* __restrict__ W, u16* __restrict__ Th, u16* __restrict__ Tl,
                        int K, int KP) {
  int n = blockIdx.x;           // 0..127 (output row)
  for (int k = threadIdx.x; k < KP; k += 128) {
    float x = (k < K) ? W[(size_t)k*128 + n] : 0.f;
    u16 h,l; split2(x,h,l);
    Th[(size_t)n*KP + k] = h; Tl[(size_t)n*KP + k] = l;
  }
}

// wuT[(dir*512 + d*4+g)][k] = Wu[k][(dir*4+g)*128 + d]
__global__ void prep_wu(const float* __restrict__ Wu, u16* __restrict__ Th, u16* __restrict__ Tl) {
  int n = blockIdx.x;    // 0..511
  int dir = blockIdx.y;  // 0..1
  int k = threadIdx.x;   // 0..127
  int d = n >> 2, g = n & 3;
  float x = Wu[(size_t)k*1024 + (dir*4+g)*128 + d];
  u16 h,l; split2(x,h,l);
  size_t o = ((size_t)dir*512 + n)*128 + k;
  Th[o]=h; Tl[o]=l;
}

// ---------------- split-bf16 MFMA GEMM ----------------
// C[m][n] = sum_k A[m][k]*B[n][k]  (both operands [row][k] with k-contiguous pairs)
// 128x128 block tile, 4 waves (64x64 each), 16x16x32 bf16 MFMA, 3 MFMAs/frag.
// EPI: 0 = write split pairs Ch/Cl
//      1 = write V^T pairs (transposed per-frame)
//      2 = qkT: scale+mask -> fp32 Cf
//      3 = pv : + residual(rh,rl) -> split pairs
//      4 = write fp32 Cf
template<int EPI>
__global__ __launch_bounds__(256) void gemm_bb(
    const u16* __restrict__ Ah, const u16* __restrict__ Al,
    const u16* __restrict__ Bh, const u16* __restrict__ Bl,
    int KP, int lda, int ldb,
    long aBatch, long bBatch, long cBatch,
    u16* __restrict__ Ch, u16* __restrict__ Cl, int ldc,
    float* __restrict__ Cf,
    const u16* __restrict__ rh, const u16* __restrict__ rl,
    const float* __restrict__ maskp, float scale)
{
  __shared__ u16 As[2][128][40];
  __shared__ u16 Bs[2][128][40];
  const int t = threadIdx.x;
  const int z = blockIdx.z;
  const int bm = blockIdx.x * 128, bn = blockIdx.y * 128;
  Ah += (size_t)z * aBatch; Al += (size_t)z * aBatch;
  Bh += (size_t)z * bBatch; Bl += (size_t)z * bBatch;

  const int lane = t & 63;
  const int w = t >> 6, wr = w >> 1, wc = w & 1;
  const int fr = lane & 15, g = lane >> 4;

  f32x4 acc[4][4] = {};

  for (int k0 = 0; k0 < KP; k0 += 32) {
    #pragma unroll
    for (int cc = 0; cc < 2; cc++) {
      int c = t + cc*256;
      int m = c >> 2, sub = c & 3;
      const size_t ga = (size_t)(bm + m)*lda + k0 + sub*8;
      const size_t gb = (size_t)(bn + m)*ldb + k0 + sub*8;
      *(int4*)&As[0][m][sub*8] = *(const int4*)(Ah + ga);
      *(int4*)&As[1][m][sub*8] = *(const int4*)(Al + ga);
      *(int4*)&Bs[0][m][sub*8] = *(const int4*)(Bh + gb);
      *(int4*)&Bs[1][m][sub*8] = *(const int4*)(Bl + gb);
    }
    __syncthreads();
    s16x8 af[4][2], bfr[4][2];
    #pragma unroll
    for (int i = 0; i < 4; i++) {
      af[i][0]  = *(const s16x8*)&As[0][wr*64 + i*16 + fr][g*8];
      af[i][1]  = *(const s16x8*)&As[1][wr*64 + i*16 + fr][g*8];
      bfr[i][0] = *(const s16x8*)&Bs[0][wc*64 + i*16 + fr][g*8];
      bfr[i][1] = *(const s16x8*)&Bs[1][wc*64 + i*16 + fr][g*8];
    }
    #pragma unroll
    for (int mi = 0; mi < 4; mi++)
      #pragma unroll
      for (int nj = 0; nj < 4; nj++)
        acc[mi][nj] = __builtin_amdgcn_mfma_f32_16x16x32_bf16(af[mi][0], bfr[nj][0], acc[mi][nj], 0,0,0);
    #pragma unroll
    for (int mi = 0; mi < 4; mi++)
      #pragma unroll
      for (int nj = 0; nj < 4; nj++)
        acc[mi][nj] = __builtin_amdgcn_mfma_f32_16x16x32_bf16(af[mi][0], bfr[nj][1], acc[mi][nj], 0,0,0);
    #pragma unroll
    for (int mi = 0; mi < 4; mi++)
      #pragma unroll
      for (int nj = 0; nj < 4; nj++)
        acc[mi][nj] = __builtin_amdgcn_mfma_f32_16x16x32_bf16(af[mi][1], bfr[nj][0], acc[mi][nj], 0,0,0);
    __syncthreads();
  }

  const int rbase = bm + wr*64, nbase = bn + wc*64;
  #pragma unroll
  for (int mi = 0; mi < 4; mi++) {
    #pragma unroll
    for (int nj = 0; nj < 4; nj++) {
      #pragma unroll
      for (int rg = 0; rg < 4; rg++) {
        int r = rbase + mi*16 + g*4 + rg;
        int n = nbase + nj*16 + fr;
        float val = acc[mi][nj][rg];
        if (EPI == 0) {
          size_t o = (size_t)r*ldc + n;
          u16 h,l; split2(val,h,l);
          Ch[o]=h; Cl[o]=l;
        } else if (EPI == 1) {      // V^T pairs: [frame][n][l]
          size_t o = ((size_t)(r >> 9)*128 + n)*512 + (r & 511);
          u16 h,l; split2(val,h,l);
          Ch[o]=h; Cl[o]=l;
        } else if (EPI == 2) {      // qkT -> fp32 S with scale+mask
          float vv = val * scale;
          if (maskp[(z>>3)*512 + n] == 0.f) vv = -1e9f;
          Cf[(size_t)z*cBatch + (size_t)r*ldc + n] = vv;
        } else if (EPI == 3) {      // pv: + q residual -> pairs
          size_t o = (size_t)z*cBatch + (size_t)r*ldc + n;
          float vv = val + (bf_to_f(rh[o]) + bf_to_f(rl[o]));
          u16 h,l; split2(vv,h,l);
          Ch[o]=h; Cl[o]=l;
        } else {                    // 4: fp32 out
          Cf[(size_t)r*ldc + n] = val;
        }
      }
    }
  }
}

// ---------------- row softmax over 512, fp32 in -> split-bf16 pairs in place ----
__global__ void softmax_split(float* __restrict__ S) {
  size_t row = blockIdx.x;
  float* p = S + row*512;
  u16* ph = (u16*)p;        // hi plane: first 1024B of row
  u16* pl = ph + 512;       // lo plane: second 1024B
  int t = threadIdx.x; // 64
  float v[8];
  float mx = -1e30f;
  #pragma unroll
  for (int i=0;i<8;i++) { v[i] = p[t + i*64]; mx = fmaxf(mx, v[i]); }
  #pragma unroll
  for (int off=32; off>0; off>>=1) mx = fmaxf(mx, __shfl_xor(mx, off));
  float sum = 0.f;
  #pragma unroll
  for (int i=0;i<8;i++) { v[i] = __expf(v[i]-mx); sum += v[i]; }
  #pragma unroll
  for (int off=32; off>0; off>>=1) sum += __shfl_xor(sum, off);
  float invs = 1.f/sum;
  #pragma unroll
  for (int i=0;i<8;i++) {
    float x = v[i]*invs;
    u16 h,l; split2(x,h,l);
    ph[t + i*64] = h; pl[t + i*64] = l;
  }
}

// ---------------- sequential SRU scan: phase-fenced register pipeline ----------------
// Grid 128 blocks (frame, channel-half), 64 threads. Chunks of 8 steps, depth-2
// prefetch, 4 rotating register buffers. Phases {load group | compute | store group}
// are fenced with sched_barrier(0) so the scheduler cannot sink loads (which
// destroyed the round-3 pipeline: VGPR_Count=80 proved buffers weren't kept live)
// and the worst-case s_waitcnt is vmcnt(48) — encodable (6-bit max 63), so waits
// never drain recent store-acks.
#define CH_ 8
#define LOADC(buf, ch) do { \
  int _c = (ch); \
  _Pragma("unroll") \
  for (int s = 0; s < CH_; s++) { \
    int stp = _c*CH_ + s; \
    int l = dirv ? 511 - stp : stp; \
    buf[s] = *(const float4*)(Ubase + (size_t)l*512); \
  } \
  __builtin_amdgcn_sched_barrier(0); \
} while(0)

#define COMPC(buf, ch) do { \
  int _c = (ch); \
  float mk[CH_]; \
  _Pragma("unroll") \
  for (int s = 0; s < CH_; s++) { \
    int stp = _c*CH_ + s; \
    int l = dirv ? 511 - stp : stp; \
    mk[s] = msk[l]; \
  } \
  unsigned pk[CH_]; \
  _Pragma("unroll") \
  for (int s = 0; s < CH_; s++) { \
    float4 u = buf[s]; \
    float xf = (u.y + bfd) + vfd*cstate; \
    float xr = (u.z + brd) + vrd*cstate; \
    float fg = 1.f/(1.f + __expf(-xf)); \
    float rg = 1.f/(1.f + __expf(-xr)); \
    float cn = fg*(cstate - u.x) + u.x; \
    if (mk[s] == 0.f) cn = cstate; \
    float h = (mk[s] == 0.f) ? 0.f : (rg*(cn - u.w) + u.w); \
    cstate = cn; \
    u16 sh_, sl_; split2(h, sh_, sl_); \
    pk[s] = (unsigned)sh_ | ((unsigned)sl_ << 16); \
  } \
  __builtin_amdgcn_sched_barrier(0); \
  _Pragma("unroll") \
  for (int s = 0; s < CH_; s++) { \
    int stp = _c*CH_ + s; \
    int l = dirv ? 511 - stp : stp; \
    hpph[(size_t)l*256] = (u16)pk[s]; \
    hppl[(size_t)l*256] = (u16)(pk[s] >> 16); \
  } \
  __builtin_amdgcn_sched_barrier(0); \
} while(0)

__global__ __launch_bounds__(64) void sru_scan(const float* __restrict__ U, const float* __restrict__ mask,
                          const float* __restrict__ vf, const float* __restrict__ vr,
                          const float* __restrict__ bf, const float* __restrict__ br,
                          u16* __restrict__ hph, u16* __restrict__ hpl,
                          int dirv) {
  const int blk = blockIdx.x;   // 0..127
  const int f = blk >> 1;       // frame
  const int hh = blk & 1;       // channel half
  const int t = threadIdx.x;    // 0..63
  const int b = f >> 3;
  __shared__ float msk[512];
  for (int i = t; i < 512; i += 64) msk[i] = mask[b*512 + i];
  __syncthreads();
  const int d = hh*64 + t;      // channel within direction
  const float vfd = vf[d], vrd = vr[d], bfd = bf[d], brd = br[d];
  const size_t fbase = (size_t)f * 512;
  const float* Ubase = U + fbase*512 + d*4;
  u16* hpph = hph + fbase*256 + (size_t)dirv*128 + d;
  u16* hppl = hpl + fbase*256 + (size_t)dirv*128 + d;

  float4 b0[CH_], b1[CH_], b2[CH_], b3[CH_];
  LOADC(b0, 0); LOADC(b1, 1);
  float cstate = 0.f;
  for (int q4 = 0; q4 < 16; q4++) {
    const int base = q4*4;
    LOADC(b2, base+2);
    COMPC(b0, base);
    LOADC(b3, base+3);
    COMPC(b1, base+1);
    if (base + 4 < 64) LOADC(b0, base+4);
    COMPC(b2, base+2);
    if (base + 5 < 64) LOADC(b1, base+5);
    COMPC(b3, base+3);
  }
}

// ---------------- mean over 8 sign-frames (reads h pairs) ----------------
__global__ void mean_kernel(const u16* __restrict__ hph, const u16* __restrict__ hpl,
                            float* __restrict__ out) {
  int i = blockIdx.x*256 + threadIdx.x;   // 0..131071, 8 channels each
  int row = i >> 5;        // b*512 + l
  int c8  = i & 31;
  int b = row >> 9, l = row & 511;
  float acc[8] = {};
  #pragma unroll
  for (int o=0;o<8;o++) {
    size_t off = ((size_t)((b*8+o)*512 + l))*256 + c8*8;
    union { int4 v; u16 s[8]; } hv, lv;
    hv.v = *(const int4*)(hph + off);
    lv.v = *(const int4*)(hpl + off);
    #pragma unroll
    for (int j=0;j<8;j++)
      acc[j] += bf_to_f(hv.s[j]) + bf_to_f(lv.s[j]);
  }
  float4 r0, r1;
  r0.x=acc[0]*0.125f; r0.y=acc[1]*0.125f; r0.z=acc[2]*0.125f; r0.w=acc[3]*0.125f;
  r1.x=acc[4]*0.125f; r1.y=acc[5]*0.125f; r1.z=acc[6]*0.125f; r1.w=acc[7]*0.125f;
  float* op = out + (size_t)row*256 + c8*8;
  *(float4*)op = r0;
  *(float4*)(op+4) = r1;
}

extern "C" void kernel_launch(void* const* d_in, const int* in_sizes, int n_in,
                              void* d_out, int out_size, void* d_ws, size_t ws_size,
                              hipStream_t stream) {
  const int*   seqs  = (const int*)d_in[0];
  const float* cords = (const float*)d_in[1];
  const float* mask  = (const float*)d_in[2];
  const float* emb   = (const float*)d_in[3];
  const float* Wq[2] = {(const float*)d_in[4],  (const float*)d_in[12]};
  const float* Wk[2] = {(const float*)d_in[5],  (const float*)d_in[13]};
  const float* Wv[2] = {(const float*)d_in[6],  (const float*)d_in[14]};
  const float* Wu[2] = {(const float*)d_in[7],  (const float*)d_in[15]};
  const float* vf[2] = {(const float*)d_in[8],  (const float*)d_in[16]};
  const float* vr[2] = {(const float*)d_in[9],  (const float*)d_in[17]};
  const float* bfp[2]= {(const float*)d_in[10], (const float*)d_in[18]};
  const float* brp[2]= {(const float*)d_in[11], (const float*)d_in[19]};

  char* base = (char*)d_ws;
  float* misc = (float*)base;                                   // 512 B
  u16* h0p_h = (u16*)(base + 512);                              // 2x 32768*288*2 B
  u16* h0p_l = h0p_h + (size_t)M_*288;
  u16* q_h = (u16*)(base + 512 + 2*(size_t)M_*288*2);
  u16* q_l = q_h + (size_t)M_*128;
  u16* k_h = q_l + (size_t)M_*128;
  u16* k_l = k_h + (size_t)M_*128;
  u16* a_h = k_h;  u16* a_l = k_l;                              // overlay (k dead after qkT)
  float* S  = (float*)(k_l + (size_t)M_*128);                   // 64MB: S -> P pairs -> U'
  float* Uprime = S;
  u16* hp_h = (u16*)((char*)S + (size_t)M_*512*4);
  u16* hp_l = hp_h + (size_t)M_*256;
  u16* vT_h = hp_h;  u16* vT_l = hp_l;                          // overlay (vT dead before scan writes hp)
  u16* wqT_h = hp_l + (size_t)M_*256;
  u16* wqT_l = wqT_h + 128*288;
  u16* wkT_h = wqT_l + 128*288;
  u16* wkT_l = wkT_h + 128*128;
  u16* wvT_h = wkT_l + 128*128;
  u16* wvT_l = wvT_h + 128*128;
  u16* wuT_h = wvT_l + 128*128;
  u16* wuT_l = wuT_h + 1024*128;

  geom_kernel<<<8, 256, 0, stream>>>(cords, mask, misc);
  build_h0<<<M_/4, 256, 0, stream>>>(seqs, cords, mask, emb, misc, h0p_h, h0p_l);

  const float scale = 0.08838834764831845f; // 1/sqrt(128)
  for (int layer = 0; layer < 2; ++layer) {
    const u16* Ah_in = layer ? hp_h : h0p_h;
    const u16* Al_in = layer ? hp_l : h0p_l;
    const int  Kq    = layer ? 256 : 259;
    const int  KPq   = layer ? 256 : 288;

    prep_wT<<<128, 128, 0, stream>>>(Wq[layer], wqT_h, wqT_l, Kq, KPq);
    prep_wT<<<128, 128, 0, stream>>>(Wk[layer], wkT_h, wkT_l, 128, 128);
    prep_wT<<<128, 128, 0, stream>>>(Wv[layer], wvT_h, wvT_l, 128, 128);
    prep_wu<<<dim3(512,2), 128, 0, stream>>>(Wu[layer], wuT_h, wuT_l);

    // q = hin @ Wq  -> pairs
    gemm_bb<0><<<dim3(256,1,1), 256, 0, stream>>>(Ah_in, Al_in, wqT_h, wqT_l,
        KPq, KPq, KPq, 0,0,0, q_h, q_l, 128, nullptr, nullptr, nullptr, nullptr, 0.f);
    // k = q @ Wk -> pairs
    gemm_bb<0><<<dim3(256,1,1), 256, 0, stream>>>(q_h, q_l, wkT_h, wkT_l,
        128, 128, 128, 0,0,0, k_h, k_l, 128, nullptr, nullptr, nullptr, nullptr, 0.f);
    // v = q @ Wv -> V^T pairs
    gemm_bb<1><<<dim3(256,1,1), 256, 0, stream>>>(q_h, q_l, wvT_h, wvT_l,
        128, 128, 128, 0,0,0, vT_h, vT_l, 0, nullptr, nullptr, nullptr, nullptr, 0.f);
    // S = q k^T * scale (masked)
    gemm_bb<2><<<dim3(4,4,64), 256, 0, stream>>>(q_h, q_l, k_h, k_l,
        128, 128, 128, 512*128, 512*128, 512*512, nullptr, nullptr, 512, S,
        nullptr, nullptr, mask, scale);
    // P = softmax(S) -> pairs (in place)
    softmax_split<<<M_, 64, 0, stream>>>(S);
    // a = P @ v + q -> pairs
    gemm_bb<3><<<dim3(4,1,64), 256, 0, stream>>>((const u16*)S, (const u16*)S + 512, vT_h, vT_l,
        512, 1024, 512, 512*1024, 128*512, 512*128, a_h, a_l, 128, nullptr,
        q_h, q_l, nullptr, 0.f);
    for (int dir = 0; dir < 2; ++dir) {
      // U' = a @ WuT(dir) -> fp32 (gate-interleaved columns d*4+g)
      gemm_bb<4><<<dim3(256,4,1), 256, 0, stream>>>(a_h, a_l,
          wuT_h + (size_t)dir*512*128, wuT_l + (size_t)dir*512*128,
          128, 128, 128, 0,0,0, nullptr, nullptr, 512, Uprime,
          nullptr, nullptr, nullptr, 0.f);
      sru_scan<<<128, 64, 0, stream>>>(Uprime, mask, vf[layer]+dir*128, vr[layer]+dir*128,
                                       bfp[layer]+dir*128, brp[layer]+dir*128,
                                       hp_h, hp_l, dir);
    }
  }
  mean_kernel<<<512, 256, 0, stream>>>(hp_h, hp_l, (float*)d_out);
}

// Round 6
// 661.052 us; speedup vs baseline: 2.3142x; 1.0355x over previous
//
#include <hip/hip_runtime.h>
#include <hip/hip_bf16.h>
#include <math.h>

#define L_    512
#define F_    64
#define M_    (F_*L_)   // 32768
#define D2_   128
#define H_    256
#define LOG2E_ 1.4426950408889634f

typedef unsigned short u16;
typedef __attribute__((ext_vector_type(8))) short s16x8;
typedef __attribute__((ext_vector_type(4))) float f32x4;

__device__ inline u16 bf_hi(float x) {
  union { float f; unsigned u; } v; v.f = x;
  unsigned r = v.u + 0x7fffu + ((v.u >> 16) & 1u);
  return (u16)(r >> 16);
}
__device__ inline float bf_to_f(u16 h) {
  union { float f; unsigned u; } v; v.u = ((unsigned)h) << 16; return v.f;
}
__device__ inline void split2(float x, u16& h, u16& l) {
  h = bf_hi(x);
  l = bf_hi(x - bf_to_f(h));   // exact residual (Sterbenz), bf16-rounded
}
__device__ inline float exp2_fast(float x) {
#if __has_builtin(__builtin_amdgcn_exp2f)
  return __builtin_amdgcn_exp2f(x);
#else
  return __expf(x * 0.6931471805599453f);
#endif
}

// ---------------- geometry: center + covariance + 3x3 eigh ----------------
__global__ void geom_kernel(const float* __restrict__ cords, const float* __restrict__ mask,
                            float* __restrict__ misc) {
  int b = blockIdx.x;
  int t = threadIdx.x;
  __shared__ float red[4][256];
  float sx=0.f, sy=0.f, sz=0.f, sm=0.f;
  for (int l = t; l < 512; l += 256) {
    float m = mask[b*512 + l];
    const float* X = cords + ((size_t)(b*512 + l)*4 + 1)*3;
    sx += X[0]*m; sy += X[1]*m; sz += X[2]*m; sm += m;
  }
  red[0][t]=sx; red[1][t]=sy; red[2][t]=sz; red[3][t]=sm;
  __syncthreads();
  for (int off=128; off>0; off>>=1) {
    if (t < off) { red[0][t]+=red[0][t+off]; red[1][t]+=red[1][t+off];
                   red[2][t]+=red[2][t+off]; red[3][t]+=red[3][t+off]; }
    __syncthreads();
  }
  float inv = 1.f/red[3][0];
  float cx = red[0][0]*inv, cy = red[1][0]*inv, cz = red[2][0]*inv;
  __syncthreads();
  __shared__ float red6[6][256];
  float c00=0,c01=0,c02=0,c11=0,c12=0,c22=0;
  for (int l = t; l < 512; l += 256) {
    float m = mask[b*512+l];
    const float* X = cords + ((size_t)(b*512+l)*4 + 1)*3;
    float x = X[0]-cx*m, y = X[1]-cy*m, z = X[2]-cz*m;
    c00+=x*x; c01+=x*y; c02+=x*z; c11+=y*y; c12+=y*z; c22+=z*z;
  }
  red6[0][t]=c00; red6[1][t]=c01; red6[2][t]=c02;
  red6[3][t]=c11; red6[4][t]=c12; red6[5][t]=c22;
  __syncthreads();
  for (int off=128; off>0; off>>=1) {
    if (t < off) for (int j=0;j<6;j++) red6[j][t]+=red6[j][t+off];
    __syncthreads();
  }
  if (t == 0) {
    double A[3][3], V[3][3];
    A[0][0]=red6[0][0]; A[0][1]=A[1][0]=red6[1][0]; A[0][2]=A[2][0]=red6[2][0];
    A[1][1]=red6[3][0]; A[1][2]=A[2][1]=red6[4][0]; A[2][2]=red6[5][0];
    for (int j=0;j<3;j++) for (int i=0;i<3;i++) V[j][i] = (i==j)?1.0:0.0;
    for (int sweep=0; sweep<10; ++sweep) {
      for (int p=0;p<2;p++) for (int q=p+1;q<3;q++) {
        double apq = A[p][q];
        if (fabs(apq) < 1e-18) continue;
        double app = A[p][p], aqq = A[q][q];
        double tau = (aqq - app) / (2.0*apq);
        double tt = (tau >= 0.0) ? 1.0/(tau + sqrt(1.0+tau*tau))
                                 : 1.0/(tau - sqrt(1.0+tau*tau));
        double cc = 1.0/sqrt(1.0+tt*tt), ss = tt*cc;
        A[p][p] = app - tt*apq;
        A[q][q] = aqq + tt*apq;
        A[p][q] = A[q][p] = 0.0;
        int r = 3 - p - q;
        double arp = A[r][p], arq = A[r][q];
        A[r][p] = A[p][r] = cc*arp - ss*arq;
        A[r][q] = A[q][r] = ss*arp + cc*arq;
        for (int rr2=0; rr2<3; ++rr2) {
          double vrp = V[rr2][p], vrq = V[rr2][q];
          V[rr2][p] = cc*vrp - ss*vrq;
          V[rr2][q] = ss*vrp + cc*vrq;
        }
      }
    }
    double w[3] = {A[0][0], A[1][1], A[2][2]};
    int idx[3] = {0,1,2};
    for (int i=0;i<2;i++) for (int j=0;j<2-i;j++)
      if (w[idx[j]] > w[idx[j+1]]) { int tmp=idx[j]; idx[j]=idx[j+1]; idx[j+1]=tmp; }
    for (int jj=0;jj<3;jj++) for (int ii=0;ii<3;ii++)
      misc[b*12 + jj*3 + ii] = (float)V[jj][idx[ii]];
    misc[b*12+9]=cx; misc[b*12+10]=cy; misc[b*12+11]=cz;
  }
}

// ---------------- build h0 pairs: [F*L][288] = [hX(3) | emb(256) | 0-pad(29)] ----
__global__ void build_h0(const int* __restrict__ seqs, const float* __restrict__ cords,
                         const float* __restrict__ mask, const float* __restrict__ emb,
                         const float* __restrict__ misc,
                         u16* __restrict__ h0h, u16* __restrict__ h0l) {
  int t = threadIdx.x;
  int r = blockIdx.x*4 + (t >> 6);
  int lane = t & 63;
  int f = r >> 9, l = r & 511;
  int b = f >> 3, o = f & 7;
  u16* rh = h0h + (size_t)r * 288;
  u16* rl = h0l + (size_t)r * 288;
  if (lane == 0) {
    float m = mask[b*512 + l];
    const float* X = cords + ((size_t)(b*512 + l)*4 + 1)*3;
    const float* mb = misc + b*12;
    float x = X[0]-mb[9]*m, y = X[1]-mb[10]*m, z = X[2]-mb[11]*m;
    #pragma unroll
    for (int i=0;i<3;i++) {
      float sgn = ((o >> (2-i)) & 1) ? 1.f : -1.f;
      float val = sgn * (mb[0+i]*x + mb[3+i]*y + mb[6+i]*z);
      u16 h,lo; split2(val,h,lo); rh[i]=h; rl[i]=lo;
    }
  }
  if (lane < 29) { rh[259+lane] = 0; rl[259+lane] = 0; }
  int s = seqs[b*512 + l];
  if (s < 0) s = 82;
  const float4 e4 = *((const float4*)(emb + (size_t)s*256) + lane);
  float ev[4] = {e4.x, e4.y, e4.z, e4.w};
  #pragma unroll
  for (int i=0;i<4;i++) {
    u16 h,lo; split2(ev[i],h,lo);
    rh[3 + lane*4 + i] = h; rl[3 + lane*4 + i] = lo;
  }
}

// ---------------- weight prep: transpose + split, zero-pad K ----------------
__global__ void prep_wT(const float* __restrict__ W, u16* __restrict__ Th, u16* __restrict__ Tl,
                        int K, int KP) {
  int n = blockIdx.x;           // 0..127 (output row)
  for (int k = threadIdx.x; k < KP; k += 128) {
    float x = (k < K) ? W[(size_t)k*128 + n] : 0.f;
    u16 h,l; split2(x,h,l);
    Th[(size_t)n*KP + k] = h; Tl[(size_t)n*KP + k] = l;
  }
}

// wuT[(dir*512 + d*4+g)][k] = Wu[k][(dir*4+g)*128 + d]; gates 1,2 pre-scaled by log2(e)
__global__ void prep_wu(const float* __restrict__ Wu, u16* __restrict__ Th, u16* __restrict__ Tl) {
  int n = blockIdx.x;    // 0..511
  int dir = blockIdx.y;  // 0..1
  int k = threadIdx.x;   // 0..127
  int d = n >> 2, g = n & 3;
  float x = Wu[(size_t)k*1024 + (dir*4+g)*128 + d];
  if (g == 1 || g == 2) x *= LOG2E_;
  u16 h,l; split2(x,h,l);
  size_t o = ((size_t)dir*512 + n)*128 + k;
  Th[o]=h; Tl[o]=l;
}

// ---------------- split-bf16 MFMA GEMM ----------------
// C[m][n] = sum_k A[m][k]*B[n][k]  (both operands [row][k] with k-contiguous pairs)
// 128x128 block tile, 4 waves (64x64 each), 16x16x32 bf16 MFMA, 3 MFMAs/frag.
// EPI: 0 = write split pairs Ch/Cl
//      1 = write V^T pairs (transposed per-frame)
//      2 = qkT: scale+mask -> fp32 Cf
//      3 = pv : + residual(rh,rl) -> split pairs
//      4 = write fp32 Cf
template<int EPI>
__global__ __launch_bounds__(256) void gemm_bb(
    const u16* __restrict__ Ah, const u16* __restrict__ Al,
    const u16* __restrict__ Bh, const u16* __restrict__ Bl,
    int KP, int lda, int ldb,
    long aBatch, long bBatch, long cBatch,
    u16* __restrict__ Ch, u16* __restrict__ Cl, int ldc,
    float* __restrict__ Cf,
    const u16* __restrict__ rh, const u16* __restrict__ rl,
    const float* __restrict__ maskp, float scale)
{
  __shared__ u16 As[2][128][40];
  __shared__ u16 Bs[2][128][40];
  const int t = threadIdx.x;
  const int z = blockIdx.z;
  const int bm = blockIdx.x * 128, bn = blockIdx.y * 128;
  Ah += (size_t)z * aBatch; Al += (size_t)z * aBatch;
  Bh += (size_t)z * bBatch; Bl += (size_t)z * bBatch;

  const int lane = t & 63;
  const int w = t >> 6, wr = w >> 1, wc = w & 1;
  const int fr = lane & 15, g = lane >> 4;

  f32x4 acc[4][4] = {};

  for (int k0 = 0; k0 < KP; k0 += 32) {
    #pragma unroll
    for (int cc = 0; cc < 2; cc++) {
      int c = t + cc*256;
      int m = c >> 2, sub = c & 3;
      const size_t ga = (size_t)(bm + m)*lda + k0 + sub*8;
      const size_t gb = (size_t)(bn + m)*ldb + k0 + sub*8;
      *(int4*)&As[0][m][sub*8] = *(const int4*)(Ah + ga);
      *(int4*)&As[1][m][sub*8] = *(const int4*)(Al + ga);
      *(int4*)&Bs[0][m][sub*8] = *(const int4*)(Bh + gb);
      *(int4*)&Bs[1][m][sub*8] = *(const int4*)(Bl + gb);
    }
    __syncthreads();
    s16x8 af[4][2], bfr[4][2];
    #pragma unroll
    for (int i = 0; i < 4; i++) {
      af[i][0]  = *(const s16x8*)&As[0][wr*64 + i*16 + fr][g*8];
      af[i][1]  = *(const s16x8*)&As[1][wr*64 + i*16 + fr][g*8];
      bfr[i][0] = *(const s16x8*)&Bs[0][wc*64 + i*16 + fr][g*8];
      bfr[i][1] = *(const s16x8*)&Bs[1][wc*64 + i*16 + fr][g*8];
    }
    #pragma unroll
    for (int mi = 0; mi < 4; mi++)
      #pragma unroll
      for (int nj = 0; nj < 4; nj++)
        acc[mi][nj] = __builtin_amdgcn_mfma_f32_16x16x32_bf16(af[mi][0], bfr[nj][0], acc[mi][nj], 0,0,0);
    #pragma unroll
    for (int mi = 0; mi < 4; mi++)
      #pragma unroll
      for (int nj = 0; nj < 4; nj++)
        acc[mi][nj] = __builtin_amdgcn_mfma_f32_16x16x32_bf16(af[mi][0], bfr[nj][1], acc[mi][nj], 0,0,0);
    #pragma unroll
    for (int mi = 0; mi < 4; mi++)
      #pragma unroll
      for (int nj = 0; nj < 4; nj++)
        acc[mi][nj] = __builtin_amdgcn_mfma_f32_16x16x32_bf16(af[mi][1], bfr[nj][0], acc[mi][nj], 0,0,0);
    __syncthreads();
  }

  const int rbase = bm + wr*64, nbase = bn + wc*64;
  #pragma unroll
  for (int mi = 0; mi < 4; mi++) {
    #pragma unroll
    for (int nj = 0; nj < 4; nj++) {
      #pragma unroll
      for (int rg = 0; rg < 4; rg++) {
        int r = rbase + mi*16 + g*4 + rg;
        int n = nbase + nj*16 + fr;
        float val = acc[mi][nj][rg];
        if (EPI == 0) {
          size_t o = (size_t)r*ldc + n;
          u16 h,l; split2(val,h,l);
          Ch[o]=h; Cl[o]=l;
        } else if (EPI == 1) {      // V^T pairs: [frame][n][l]
          size_t o = ((size_t)(r >> 9)*128 + n)*512 + (r & 511);
          u16 h,l; split2(val,h,l);
          Ch[o]=h; Cl[o]=l;
        } else if (EPI == 2) {      // qkT -> fp32 S with scale+mask
          float vv = val * scale;
          if (maskp[(z>>3)*512 + n] == 0.f) vv = -1e9f;
          Cf[(size_t)z*cBatch + (size_t)r*ldc + n] = vv;
        } else if (EPI == 3) {      // pv: + q residual -> pairs
          size_t o = (size_t)z*cBatch + (size_t)r*ldc + n;
          float vv = val + (bf_to_f(rh[o]) + bf_to_f(rl[o]));
          u16 h,l; split2(vv,h,l);
          Ch[o]=h; Cl[o]=l;
        } else {                    // 4: fp32 out
          Cf[(size_t)r*ldc + n] = val;
        }
      }
    }
  }
}

// ---------------- row softmax over 512, fp32 in -> split-bf16 pairs in place ----
__global__ void softmax_split(float* __restrict__ S) {
  size_t row = blockIdx.x;
  float* p = S + row*512;
  u16* ph = (u16*)p;        // hi plane: first 1024B of row
  u16* pl = ph + 512;       // lo plane: second 1024B
  int t = threadIdx.x; // 64
  float v[8];
  float mx = -1e30f;
  #pragma unroll
  for (int i=0;i<8;i++) { v[i] = p[t + i*64]; mx = fmaxf(mx, v[i]); }
  #pragma unroll
  for (int off=32; off>0; off>>=1) mx = fmaxf(mx, __shfl_xor(mx, off));
  float sum = 0.f;
  #pragma unroll
  for (int i=0;i<8;i++) { v[i] = __expf(v[i]-mx); sum += v[i]; }
  #pragma unroll
  for (int off=32; off>0; off>>=1) sum += __shfl_xor(sum, off);
  float invs = 1.f/sum;
  #pragma unroll
  for (int i=0;i<8;i++) {
    float x = v[i]*invs;
    u16 h,l; split2(x,h,l);
    ph[t + i*64] = h; pl[t + i*64] = l;
  }
}

// ---------------- sequential SRU scan: branch-free register pipeline ----------------
// Grid 128 blocks (frame, channel-half), 64 threads (1 wave). 64 chunks of 8 steps.
// Prologue loads chunks 0,1; steady-state loop (15 iters x 4 chunk-pairs) issues
// LOADC(q+2) then COMPC(q) -- ALL unconditional so live ranges / vmcnt counts are
// statically exact (worst wait vmcnt(48), 6-bit encodable); epilogue peels chunks
// 60..63. launch_bounds(64,1) gives the allocator the full budget: the 4 buffers
// (128 VGPR) MUST stay register-resident (diagnostic: VGPR_Count ~180).
#define CH_ 8
#define LOADC(buf, ch) do { \
  int _c = (ch); \
  _Pragma("unroll") \
  for (int s = 0; s < CH_; s++) { \
    int l = (_c*CH_ + s) ^ lxor; \
    buf[s] = *(const float4*)(Ubase + (size_t)l*512); \
  } \
  __builtin_amdgcn_sched_barrier(0); \
} while(0)

#define COMPC(buf, ch) do { \
  int _c = (ch); \
  float mk[CH_]; \
  _Pragma("unroll") \
  for (int s = 0; s < CH_; s++) { \
    int l = (_c*CH_ + s) ^ lxor; \
    mk[s] = msk[l]; \
  } \
  unsigned pk[CH_]; \
  _Pragma("unroll") \
  for (int s = 0; s < CH_; s++) { \
    float4 u = buf[s]; \
    float xf = (u.y + bfd) + vfd*cstate; \
    float xr = (u.z + brd) + vrd*cstate; \
    float fg = 1.f/(1.f + exp2_fast(-xf)); \
    float rg = 1.f/(1.f + exp2_fast(-xr)); \
    float cn = fg*(cstate - u.x) + u.x; \
    if (mk[s] == 0.f) cn = cstate; \
    float h = (mk[s] == 0.f) ? 0.f : (rg*(cn - u.w) + u.w); \
    cstate = cn; \
    u16 sh_, sl_; split2(h, sh_, sl_); \
    pk[s] = (unsigned)sh_ | ((unsigned)sl_ << 16); \
  } \
  __builtin_amdgcn_sched_barrier(0); \
  _Pragma("unroll") \
  for (int s = 0; s < CH_; s++) { \
    int l = (_c*CH_ + s) ^ lxor; \
    hpph[(size_t)l*256] = (u16)pk[s]; \
    hppl[(size_t)l*256] = (u16)(pk[s] >> 16); \
  } \
  __builtin_amdgcn_sched_barrier(0); \
} while(0)

__global__ __launch_bounds__(64, 1) void sru_scan(const float* __restrict__ U, const float* __restrict__ mask,
                          const float* __restrict__ vf, const float* __restrict__ vr,
                          const float* __restrict__ bf, const float* __restrict__ br,
                          u16* __restrict__ hph, u16* __restrict__ hpl,
                          int dirv) {
  const int blk = blockIdx.x;   // 0..127
  const int f = blk >> 1;       // frame
  const int hh = blk & 1;       // channel half
  const int t = threadIdx.x;    // 0..63
  const int b = f >> 3;
  __shared__ float msk[512];
  for (int i = t; i < 512; i += 64) msk[i] = mask[b*512 + i];
  __syncthreads();
  const int lxor = dirv ? 511 : 0;        // l = step ^ lxor  (511-step == 511^step)
  const int d = hh*64 + t;                // channel within direction
  const float vfd = vf[d]*LOG2E_, vrd = vr[d]*LOG2E_;
  const float bfd = bf[d]*LOG2E_, brd = br[d]*LOG2E_;
  const size_t fbase = (size_t)f * 512;
  const float* Ubase = U + fbase*512 + d*4;
  u16* hpph = hph + fbase*256 + (size_t)dirv*128 + d;
  u16* hppl = hpl + fbase*256 + (size_t)dirv*128 + d;

  float4 b0[CH_], b1[CH_], b2[CH_], b3[CH_];
  LOADC(b0, 0); LOADC(b1, 1);
  float cstate = 0.f;
  #pragma unroll 1
  for (int q4 = 0; q4 < 15; q4++) {
    const int base = q4*4;
    LOADC(b2, base+2);
    COMPC(b0, base);
    LOADC(b3, base+3);
    COMPC(b1, base+1);
    LOADC(b0, base+4);
    COMPC(b2, base+2);
    LOADC(b1, base+5);
    COMPC(b3, base+3);
  }
  // epilogue: chunks 60..63 (b0=60, b1=61 already loaded)
  LOADC(b2, 62);
  COMPC(b0, 60);
  LOADC(b3, 63);
  COMPC(b1, 61);
  COMPC(b2, 62);
  COMPC(b3, 63);
}

// ---------------- mean over 8 sign-frames (reads h pairs) ----------------
__global__ void mean_kernel(const u16* __restrict__ hph, const u16* __restrict__ hpl,
                            float* __restrict__ out) {
  int i = blockIdx.x*256 + threadIdx.x;   // 0..131071, 8 channels each
  int row = i >> 5;        // b*512 + l
  int c8  = i & 31;
  int b = row >> 9, l = row & 511;
  float acc[8] = {};
  #pragma unroll
  for (int o=0;o<8;o++) {
    size_t off = ((size_t)((b*8+o)*512 + l))*256 + c8*8;
    union { int4 v; u16 s[8]; } hv, lv;
    hv.v = *(const int4*)(hph + off);
    lv.v = *(const int4*)(hpl + off);
    #pragma unroll
    for (int j=0;j<8;j++)
      acc[j] += bf_to_f(hv.s[j]) + bf_to_f(lv.s[j]);
  }
  float4 r0, r1;
  r0.x=acc[0]*0.125f; r0.y=acc[1]*0.125f; r0.z=acc[2]*0.125f; r0.w=acc[3]*0.125f;
  r1.x=acc[4]*0.125f; r1.y=acc[5]*0.125f; r1.z=acc[6]*0.125f; r1.w=acc[7]*0.125f;
  float* op = out + (size_t)row*256 + c8*8;
  *(float4*)op = r0;
  *(float4*)(op+4) = r1;
}

extern "C" void kernel_launch(void* const* d_in, const int* in_sizes, int n_in,
                              void* d_out, int out_size, void* d_ws, size_t ws_size,
                              hipStream_t stream) {
  const int*   seqs  = (const int*)d_in[0];
  const float* cords = (const float*)d_in[1];
  const float* mask  = (const float*)d_in[2];
  const float* emb   = (const float*)d_in[3];
  const float* Wq[2] = {(const float*)d_in[4],  (const float*)d_in[12]};
  const float* Wk[2] = {(const float*)d_in[5],  (const float*)d_in[13]};
  const float* Wv[2] = {(const float*)d_in[6],  (const float*)d_in[14]};
  const float* Wu[2] = {(const float*)d_in[7],  (const float*)d_in[15]};
  const float* vf[2] = {(const float*)d_in[8],  (const float*)d_in[16]};
  const float* vr[2] = {(const float*)d_in[9],  (const float*)d_in[17]};
  const float* bfp[2]= {(const float*)d_in[10], (const float*)d_in[18]};
  const float* brp[2]= {(const float*)d_in[11], (const float*)d_in[19]};

  char* base = (char*)d_ws;
  float* misc = (float*)base;                                   // 512 B
  u16* h0p_h = (u16*)(base + 512);                              // 2x 32768*288*2 B
  u16* h0p_l = h0p_h + (size_t)M_*288;
  u16* q_h = (u16*)(base + 512 + 2*(size_t)M_*288*2);
  u16* q_l = q_h + (size_t)M_*128;
  u16* k_h = q_l + (size_t)M_*128;
  u16* k_l = k_h + (size_t)M_*128;
  u16* a_h = k_h;  u16* a_l = k_l;                              // overlay (k dead after qkT)
  float* S  = (float*)(k_l + (size_t)M_*128);                   // 64MB: S -> P pairs -> U'
  float* Uprime = S;
  u16* hp_h = (u16*)((char*)S + (size_t)M_*512*4);
  u16* hp_l = hp_h + (size_t)M_*256;
  u16* vT_h = hp_h;  u16* vT_l = hp_l;                          // overlay (vT dead before scan writes hp)
  u16* wqT_h = hp_l + (size_t)M_*256;
  u16* wqT_l = wqT_h + 128*288;
  u16* wkT_h = wqT_l + 128*288;
  u16* wkT_l = wkT_h + 128*128;
  u16* wvT_h = wkT_l + 128*128;
  u16* wvT_l = wvT_h + 128*128;
  u16* wuT_h = wvT_l + 128*128;
  u16* wuT_l = wuT_h + 1024*128;

  geom_kernel<<<8, 256, 0, stream>>>(cords, mask, misc);
  build_h0<<<M_/4, 256, 0, stream>>>(seqs, cords, mask, emb, misc, h0p_h, h0p_l);

  const float scale = 0.08838834764831845f; // 1/sqrt(128)
  for (int layer = 0; layer < 2; ++layer) {
    const u16* Ah_in = layer ? hp_h : h0p_h;
    const u16* Al_in = layer ? hp_l : h0p_l;
    const int  Kq    = layer ? 256 : 259;
    const int  KPq   = layer ? 256 : 288;

    prep_wT<<<128, 128, 0, stream>>>(Wq[layer], wqT_h, wqT_l, Kq, KPq);
    prep_wT<<<128, 128, 0, stream>>>(Wk[layer], wkT_h, wkT_l, 128, 128);
    prep_wT<<<128, 128, 0, stream>>>(Wv[layer], wvT_h, wvT_l, 128, 128);
    prep_wu<<<dim3(512,2), 128, 0, stream>>>(Wu[layer], wuT_h, wuT_l);

    // q = hin @ Wq  -> pairs
    gemm_bb<0><<<dim3(256,1,1), 256, 0, stream>>>(Ah_in, Al_in, wqT_h, wqT_l,
        KPq, KPq, KPq, 0,0,0, q_h, q_l, 128, nullptr, nullptr, nullptr, nullptr, 0.f);
    // k = q @ Wk -> pairs
    gemm_bb<0><<<dim3(256,1,1), 256, 0, stream>>>(q_h, q_l, wkT_h, wkT_l,
        128, 128, 128, 0,0,0, k_h, k_l, 128, nullptr, nullptr, nullptr, nullptr, 0.f);
    // v = q @ Wv -> V^T pairs
    gemm_bb<1><<<dim3(256,1,1), 256, 0, stream>>>(q_h, q_l, wvT_h, wvT_l,
        128, 128, 128, 0,0,0, vT_h, vT_l, 0, nullptr, nullptr, nullptr, nullptr, 0.f);
    // S = q k^T * scale (masked)
    gemm_bb<2><<<dim3(4,4,64), 256, 0, stream>>>(q_h, q_l, k_h, k_l,
        128, 128, 128, 512*128, 512*128, 512*512, nullptr, nullptr, 512, S,
        nullptr, nullptr, mask, scale);
    // P = softmax(S) -> pairs (in place)
    softmax_split<<<M_, 64, 0, stream>>>(S);
    // a = P @ v + q -> pairs
    gemm_bb<3><<<dim3(4,1,64), 256, 0, stream>>>((const u16*)S, (const u16*)S + 512, vT_h, vT_l,
        512, 1024, 512, 512*1024, 128*512, 512*128, a_h, a_l, 128, nullptr,
        q_h, q_l, nullptr, 0.f);
    for (int dir = 0; dir < 2; ++dir) {
      // U' = a @ WuT(dir) -> fp32 (gate-interleaved columns d*4+g; gates 1,2 log2e-scaled)
      gemm_bb<4><<<dim3(256,4,1), 256, 0, stream>>>(a_h, a_l,
          wuT_h + (size_t)dir*512*128, wuT_l + (size_t)dir*512*128,
          128, 128, 128, 0,0,0, nullptr, nullptr, 512, Uprime,
          nullptr, nullptr, nullptr, 0.f);
      sru_scan<<<128, 64, 0, stream>>>(Uprime, mask, vf[layer]+dir*128, vr[layer]+dir*128,
                                       bfp[layer]+dir*128, brp[layer]+dir*128,
                                       hp_h, hp_l, dir);
    }
  }
  mean_kernel<<<512, 256, 0, stream>>>(hp_h, hp_l, (float*)d_out);
}